// Round 14
// baseline (366.582 us; speedup 1.0000x reference)
//
#include <hip/hip_runtime.h>
#include <stdint.h>
#include <math.h>

#define TOK 2048
#define DMODEL 4096
#define QKV_LD 5120   // q(4096) | k(1024); V goes transposed to vtg
#define KVB 64

typedef __attribute__((ext_vector_type(8))) short short8;
typedef __attribute__((ext_vector_type(4))) short short4v;
typedef __attribute__((ext_vector_type(8))) __bf16 bf16x8;
typedef __attribute__((ext_vector_type(4))) float f32x4;

__device__ __forceinline__ unsigned short f2bf(float f) {
  unsigned u = __float_as_uint(f);
  u += 0x7fffu + ((u >> 16) & 1u);   // RNE
  return (unsigned short)(u >> 16);
}

__device__ __forceinline__ void gl16(const void* g, void* l) {
  __builtin_amdgcn_global_load_lds((__attribute__((address_space(1))) void*)g,
                                   (__attribute__((address_space(3))) void*)l,
                                   16, 0, 0);
}

__device__ __forceinline__ f32x4 mfma16(short8 a, short8 b, f32x4 c) {
  return __builtin_amdgcn_mfma_f32_16x16x32_bf16(__builtin_bit_cast(bf16x8, a),
                                                 __builtin_bit_cast(bf16x8, b),
                                                 c, 0, 0, 0);
}

__device__ __forceinline__ float fexp2(float x) {
  float r;
  asm("v_exp_f32 %0, %1" : "=v"(r) : "v"(x));
  return r;
}

template <int N>
__device__ __forceinline__ void waitvm() {
  if constexpr (N == 0) asm volatile("s_waitcnt vmcnt(0)" ::: "memory");
  else if constexpr (N == 2) asm volatile("s_waitcnt vmcnt(2)" ::: "memory");
  else if constexpr (N == 3) asm volatile("s_waitcnt vmcnt(3)" ::: "memory");
  else static_assert(N == 0 || N == 2 || N == 3, "add literal");
}

__device__ __forceinline__ void waitvm0() {
  asm volatile("s_waitcnt vmcnt(0)" ::: "memory");
}

// ---------------- RMSNorm: fp32 x -> bf16 h ----------------
__global__ __launch_bounds__(256) void k_rmsnorm(const float* __restrict__ x,
                                                 const float* __restrict__ w,
                                                 unsigned short* __restrict__ h) {
  const int row = blockIdx.x;
  const float* xr = x + (size_t)row * DMODEL;
  float4 v[4];
  float ss = 0.f;
#pragma unroll
  for (int i = 0; i < 4; ++i) {
    v[i] = *(const float4*)(xr + threadIdx.x * 4 + i * 1024);
    ss += v[i].x * v[i].x + v[i].y * v[i].y + v[i].z * v[i].z + v[i].w * v[i].w;
  }
#pragma unroll
  for (int m = 1; m < 64; m <<= 1) ss += __shfl_xor(ss, m, 64);
  __shared__ float ws4[4];
  if ((threadIdx.x & 63) == 0) ws4[threadIdx.x >> 6] = ss;
  __syncthreads();
  const float scale = rsqrtf((ws4[0] + ws4[1] + ws4[2] + ws4[3]) * (1.0f / DMODEL) + 1e-5f);
  unsigned short* hr = h + (size_t)row * DMODEL;
#pragma unroll
  for (int i = 0; i < 4; ++i) {
    int col = threadIdx.x * 4 + i * 1024;
    float4 wv = *(const float4*)(w + col);
    uint2 o;
    o.x = (unsigned)f2bf(v[i].x * scale * wv.x) | ((unsigned)f2bf(v[i].y * scale * wv.y) << 16);
    o.y = (unsigned)f2bf(v[i].z * scale * wv.z) | ((unsigned)f2bf(v[i].w * scale * wv.w) << 16);
    *(uint2*)(hr + col) = o;
  }
}

// ------- Weight convert+transpose: W[K][N] fp32 -> WT[N][K] bf16 -------
__global__ __launch_bounds__(256) void k_wconvert(const float* __restrict__ W,
                                                  unsigned short* __restrict__ WT,
                                                  int K, int N) {
  __shared__ unsigned short tile[64][65];
  const int n0 = blockIdx.x * 64, k0 = blockIdx.y * 64;
  const int t = threadIdx.x;
  {
    const int r = t >> 2, c0 = (t & 3) * 16;
    const float* src = W + (size_t)(k0 + r) * N + n0 + c0;
#pragma unroll
    for (int i = 0; i < 4; ++i) {
      float4 f = *(const float4*)(src + i * 4);
      tile[r][c0 + i * 4 + 0] = f2bf(f.x);
      tile[r][c0 + i * 4 + 1] = f2bf(f.y);
      tile[r][c0 + i * 4 + 2] = f2bf(f.z);
      tile[r][c0 + i * 4 + 3] = f2bf(f.w);
    }
  }
  __syncthreads();
  {
    const int n = t >> 2, c0 = (t & 3) * 16;
    unsigned short* dst = WT + (size_t)(n0 + n) * K + k0 + c0;
    unsigned short v[16];
#pragma unroll
    for (int i = 0; i < 16; ++i) v[i] = tile[c0 + i][n];
    uint4 o0, o1;
    o0.x = v[0] | ((unsigned)v[1] << 16);  o0.y = v[2] | ((unsigned)v[3] << 16);
    o0.z = v[4] | ((unsigned)v[5] << 16);  o0.w = v[6] | ((unsigned)v[7] << 16);
    o1.x = v[8] | ((unsigned)v[9] << 16);  o1.y = v[10] | ((unsigned)v[11] << 16);
    o1.z = v[12] | ((unsigned)v[13] << 16); o1.w = v[14] | ((unsigned)v[15] << 16);
    *(uint4*)dst = o0;
    *(uint4*)(dst + 8) = o1;
  }
}

// ======== Counted 2-barrier GEMM (round-13 proven, 2-blocks/CU tiles) ========
__device__ __forceinline__ short8 rdfrag(const unsigned short* buf, int row, int kc) {
  return *(const short8*)((const char*)buf + row * 128 + ((kc ^ (row & 7)) << 4));
}

template <int BM, int BN, int HALF>
__device__ __forceinline__ void stage_half(const unsigned short* __restrict__ A,
                                           const unsigned short* __restrict__ BT,
                                           unsigned short* __restrict__ buf,
                                           int m0, int n0, int K, int kt, int tid) {
  constexpr int LA = BM / 64, LB = BN / 64;
  constexpr int H0A = LA / 2, H0B = (LB + 1) / 2;
  constexpr int A0 = HALF ? H0A : 0, A1 = HALF ? LA : H0A;
  constexpr int B0 = HALF ? H0B : 0, B1 = HALF ? LB : H0B;
  unsigned short* bbuf = buf + BM * 64;
#pragma unroll
  for (int i = A0; i < A1; ++i) {
    const int s = i * 512 + tid, row = s >> 3, ch = s & 7;
    gl16(A + (size_t)(m0 + row) * K + kt + ((ch ^ (row & 7)) << 3), (char*)buf + s * 16);
  }
#pragma unroll
  for (int i = B0; i < B1; ++i) {
    const int s = i * 512 + tid, row = s >> 3, ch = s & 7;
    gl16(BT + (size_t)(n0 + row) * K + kt + ((ch ^ (row & 7)) << 3), (char*)bbuf + s * 16);
  }
}

// MODE=0: qkv epilogue with fused RoPE (cols<5120 -> roped bf16 qkvb;
//         cols>=5120 -> vtg transposed).  MODE=1: fp32 C = acc + resid.
template <int BM, int BN, int MODE>
__global__ __launch_bounds__(512, 2) void k_gemm_big(const unsigned short* __restrict__ A,
                                                     const unsigned short* __restrict__ BT,
                                                     const float* __restrict__ resid,
                                                     void* __restrict__ Cout,
                                                     unsigned short* __restrict__ vtg,
                                                     const float* __restrict__ rc,
                                                     const float* __restrict__ rs,
                                                     int M, int N, int K) {
  extern __shared__ __align__(16) unsigned short lds[];
  constexpr int MREP = BM / 32;
  constexpr int NREP = BN / 64;
  constexpr int MH = MREP / 2;
  constexpr int TILE = (BM + BN) * 64;
  constexpr int LA = BM / 64, LB = BN / 64;
  constexpr int H0 = LA / 2 + (LB + 1) / 2;

  const int tid = threadIdx.x, lane = tid & 63;
  const int w = tid >> 6, wm = w >> 2, wn = w & 3;
  const int lr = lane & 15, lh = lane >> 4;

  // 2-D XCD chunking over the 16x32 panel grid (bijective, 64 blocks/XCD)
  const int wg0 = blockIdx.x;
  const int xcd = wg0 & 7, l = wg0 >> 3;
  const int m0 = (((xcd >> 2) << 3) + (l >> 3)) * BM;
  const int n0 = (((xcd & 3) << 3) + (l & 7)) * BN;

  const f32x4 zf = {0.f, 0.f, 0.f, 0.f};
  f32x4 acc[MREP][NREP];
#pragma unroll
  for (int i = 0; i < MREP; ++i) {
#pragma unroll
    for (int j = 0; j < NREP; ++j) acc[i][j] = zf;
  }

  const int arow0 = wm * (BM / 2);
  const int brow0 = wn * (BN / 4);
  const int NT = K >> 6;
  int cur = 0;

  stage_half<BM, BN, 0>(A, BT, lds, m0, n0, K, 0, tid);
  stage_half<BM, BN, 1>(A, BT, lds, m0, n0, K, 0, tid);

  for (int t = 0; t < NT; ++t) {
    const unsigned short* abuf = lds + cur * TILE;
    const unsigned short* bbuf = abuf + BM * 64;
    unsigned short* nbuf = lds + (cur ^ 1) * TILE;
    const bool pre = (t + 1 < NT);
    const int ktn = (t + 1) << 6;

    short8 bfr[NREP], afr[MH];
    // ---- P0: stage h0(t+1), counted wait for tile t, barrier, kk0 mh0
    if (pre) {
      stage_half<BM, BN, 0>(A, BT, nbuf, m0, n0, K, ktn, tid);
      waitvm<H0>();
    } else {
      waitvm<0>();
    }
    __builtin_amdgcn_s_barrier();
#pragma unroll
    for (int nr = 0; nr < NREP; ++nr) bfr[nr] = rdfrag(bbuf, brow0 + nr * 16 + lr, lh);
#pragma unroll
    for (int mi = 0; mi < MH; ++mi) afr[mi] = rdfrag(abuf, arow0 + mi * 16 + lr, lh);
    __builtin_amdgcn_s_setprio(1);
#pragma unroll
    for (int mi = 0; mi < MH; ++mi) {
#pragma unroll
      for (int nr = 0; nr < NREP; ++nr)
        acc[mi][nr] = mfma16(afr[mi], bfr[nr], acc[mi][nr]);
    }
    __builtin_amdgcn_s_setprio(0);
    // ---- P1: stage h1(t+1) || kk0 mh1
    if (pre) stage_half<BM, BN, 1>(A, BT, nbuf, m0, n0, K, ktn, tid);
#pragma unroll
    for (int mi = 0; mi < MH; ++mi) afr[mi] = rdfrag(abuf, arow0 + (MH + mi) * 16 + lr, lh);
    __builtin_amdgcn_s_setprio(1);
#pragma unroll
    for (int mi = 0; mi < MH; ++mi) {
#pragma unroll
      for (int nr = 0; nr < NREP; ++nr)
        acc[MH + mi][nr] = mfma16(afr[mi], bfr[nr], acc[MH + mi][nr]);
    }
    __builtin_amdgcn_s_setprio(0);
    // ---- P2: kk1 mh0
#pragma unroll
    for (int nr = 0; nr < NREP; ++nr) bfr[nr] = rdfrag(bbuf, brow0 + nr * 16 + lr, 4 + lh);
#pragma unroll
    for (int mi = 0; mi < MH; ++mi) afr[mi] = rdfrag(abuf, arow0 + mi * 16 + lr, 4 + lh);
    __builtin_amdgcn_s_setprio(1);
#pragma unroll
    for (int mi = 0; mi < MH; ++mi) {
#pragma unroll
      for (int nr = 0; nr < NREP; ++nr)
        acc[mi][nr] = mfma16(afr[mi], bfr[nr], acc[mi][nr]);
    }
    __builtin_amdgcn_s_setprio(0);
    // ---- P3: kk1 mh1; all reads done -> barrier (frees buf[cur]) -> MFMA
#pragma unroll
    for (int mi = 0; mi < MH; ++mi) afr[mi] = rdfrag(abuf, arow0 + (MH + mi) * 16 + lr, 4 + lh);
    asm volatile("s_waitcnt lgkmcnt(0)" ::: "memory");
    __builtin_amdgcn_s_barrier();
    __builtin_amdgcn_s_setprio(1);
#pragma unroll
    for (int mi = 0; mi < MH; ++mi) {
#pragma unroll
      for (int nr = 0; nr < NREP; ++nr)
        acc[MH + mi][nr] = mfma16(afr[mi], bfr[nr], acc[MH + mi][nr]);
    }
    __builtin_amdgcn_s_setprio(0);
    cur ^= 1;
  }

  // ---- epilogue: C row = 4*lh + r, col = lr within each 16x16 tile
#pragma unroll
  for (int ai = 0; ai < MREP; ++ai) {
#pragma unroll
    for (int ni = 0; ni < NREP; ++ni) {
      const int colg = n0 + wn * (BN / 4) + ni * 16 + lr;
      const int rowg0 = m0 + wm * (BM / 2) + ai * 16 + 4 * lh;
      if (MODE == 1) {
#pragma unroll
        for (int r = 0; r < 4; ++r)
          ((float*)Cout)[(size_t)(rowg0 + r) * N + colg] =
              acc[ai][ni][r] + resid[(size_t)(rowg0 + r) * N + colg];
      } else if (colg >= 5120) {
        short4v o;
#pragma unroll
        for (int r = 0; r < 4; ++r) o[r] = (short)f2bf(acc[ai][ni][r]);
        *(short4v*)(vtg + (size_t)(colg - 5120) * TOK + rowg0) = o;
      } else {
        // fused RoPE: pair (even,odd) cols live in adjacent lanes
        const int d = colg & 127;
#pragma unroll
        for (int r = 0; r < 4; ++r) {
          const int row = rowg0 + r;
          const float v = acc[ai][ni][r];
          const float p = __shfl_xor(v, 1, 64);
          const float c = rc[row * 128 + d];
          const float s = rs[row * 128 + d];
          const float y = (lr & 1) ? fmaf(p, s, v * c) : fmaf(-p, s, v * c);
          ((unsigned short*)Cout)[(size_t)row * QKV_LD + colg] = f2bf(y);
        }
      }
    }
  }
}

// ---------------- Flash attention: parallel-pair, shared KV ----------------
// grid (16 pairs, 32 heads); 512 threads = 8 waves. Waves 0-3 own q-tile bx,
// waves 4-7 own q-tile 31-bx; both consume the SAME staged K/V stream
// (single-barrier double-buffered pipeline). Per-wave compute identical to
// the round-9 kernel; compute guarded by wave-uniform (t < nt_local); all
// barriers & staging unconditional. P in per-wave LDS, stride 64 + XOR-chunk
// swizzle (write chunk = (col>>3)^(row&7); read same involution).
__global__ __launch_bounds__(512) void k_attn(const unsigned short* __restrict__ qkv,
                                              const unsigned short* __restrict__ vtg,
                                              unsigned short* __restrict__ aout) {
  extern __shared__ __align__(16) unsigned short sm[];
  unsigned short* const KsB = sm;                    // [2][KVB*128]  32KB
  unsigned short* const VtB = sm + 2 * KVB * 128;    // [2][128*KVB]  32KB
  unsigned short* const Ps = sm + 4 * KVB * 128;     // [8][16*64]    16KB
  const int head = blockIdx.y;
  const int hkv = head >> 2;
  const int tid = threadIdx.x, lane = tid & 63, w = tid >> 6;
  const int grp = w >> 2, wl = w & 3;
  const int lr = lane & 15, lh = lane >> 4;
  const float scale2 = 0.08838834764831845f * 1.44269504088896340736f;  // /sqrt(128)*log2(e)
  const f32x4 zf = {0.f, 0.f, 0.f, 0.f};

  const int bx = blockIdx.x;
  const int qt = grp ? (31 - bx) : bx;
  const int q0 = qt * 64;
  const int ntl = qt + 1;          // tiles this wave-group computes
  const int NT = 32 - bx;          // max(bx+1, 32-bx) for bx<16

  auto stageKV = [&](int kvt, int buf) {
    unsigned short* Ksn = KsB + buf * (KVB * 128);
    unsigned short* Vtn = VtB + buf * (128 * KVB);
    const int kvn = kvt * KVB;
#pragma unroll
    for (int c = 0; c < 2; ++c) {
      const int s = c * 512 + tid;
      const int row = s >> 4, cp = s & 15;
      gl16(qkv + (size_t)(kvn + row) * QKV_LD + 4096 + hkv * 128 + ((cp ^ (row & 7)) * 8),
           (char*)Ksn + (c * 512 + w * 64) * 16);
    }
#pragma unroll
    for (int c = 0; c < 2; ++c) {
      const int s = c * 512 + tid;
      const int row = s >> 3, cp = s & 7;
      gl16(vtg + (size_t)(hkv * 128 + row) * TOK + kvn + ((cp ^ (row & 7)) * 8),
           (char*)Vtn + (c * 512 + w * 64) * 16);
    }
  };

  short8 qf[4];
  {
    const unsigned short* qbase = qkv + (size_t)(q0 + wl * 16 + lr) * QKV_LD + head * 128;
#pragma unroll
    for (int kd = 0; kd < 4; ++kd) qf[kd] = *(const short8*)(qbase + kd * 32 + lh * 8);
  }
  f32x4 oacc[8];
#pragma unroll
  for (int vt = 0; vt < 8; ++vt) oacc[vt] = zf;
  float Mr[4], Lp[4];
#pragma unroll
  for (int r = 0; r < 4; ++r) { Mr[r] = -INFINITY; Lp[r] = 0.f; }

  int cur = 0;
  stageKV(0, 0);

  for (int t = 0; t < NT; ++t) {
    const unsigned short* Ks = KsB + cur * (KVB * 128);
    const unsigned short* Vt = VtB + cur * (128 * KVB);
    const int kv0 = t * KVB;
    waitvm0();
    __builtin_amdgcn_s_barrier();
    __builtin_amdgcn_sched_barrier(0);
    if (t + 1 < NT) stageKV(t + 1, cur ^ 1);

    if (t < ntl) {    // wave-uniform guard; barriers stay outside
      // QK^T: S[16 q][64 kv] per wave
      f32x4 sacc[4];
#pragma unroll
      for (int ct = 0; ct < 4; ++ct) {
        sacc[ct] = zf;
        const int row = ct * 16 + lr;
#pragma unroll
        for (int kd = 0; kd < 4; ++kd) {
          const short8 kf = *(const short8*)((const char*)Ks + row * 256 +
                                             (((kd * 4 + lh) ^ (row & 7)) * 16));
          sacc[ct] = mfma16(qf[kd], kf, sacc[ct]);
        }
      }

      // softmax: scale, (diag-only) mask, max-reduce; defer-max skip; exp2
      const bool diag = (t == qt);
      float sv[4][4], gmax[4];
#pragma unroll
      for (int r = 0; r < 4; ++r) {
        float s0 = sacc[0][r] * scale2;
        float s1 = sacc[1][r] * scale2;
        float s2 = sacc[2][r] * scale2;
        float s3 = sacc[3][r] * scale2;
        if (diag) {
          const int qrow = q0 + wl * 16 + 4 * lh + r;
          if (kv0 + lr > qrow) s0 = -INFINITY;
          if (kv0 + 16 + lr > qrow) s1 = -INFINITY;
          if (kv0 + 32 + lr > qrow) s2 = -INFINITY;
          if (kv0 + 48 + lr > qrow) s3 = -INFINITY;
        }
        float tmax = fmaxf(fmaxf(s0, s1), fmaxf(s2, s3));
        tmax = fmaxf(tmax, __shfl_xor(tmax, 1, 16));
        tmax = fmaxf(tmax, __shfl_xor(tmax, 2, 16));
        tmax = fmaxf(tmax, __shfl_xor(tmax, 4, 16));
        tmax = fmaxf(tmax, __shfl_xor(tmax, 8, 16));
        gmax[r] = tmax;
        sv[r][0] = s0; sv[r][1] = s1; sv[r][2] = s2; sv[r][3] = s3;
      }
      const int cond = (gmax[0] <= Mr[0] + 8.f) && (gmax[1] <= Mr[1] + 8.f) &&
                       (gmax[2] <= Mr[2] + 8.f) && (gmax[3] <= Mr[3] + 8.f);
      if (!__all(cond)) {
        float scv[4];
#pragma unroll
        for (int r = 0; r < 4; ++r) {
          const float mnew = fmaxf(Mr[r], gmax[r]);
          scv[r] = fexp2(Mr[r] - mnew);
          Mr[r] = mnew;
          Lp[r] *= scv[r];
        }
#pragma unroll
        for (int vt = 0; vt < 8; ++vt) {
#pragma unroll
          for (int r = 0; r < 4; ++r) oacc[vt][r] *= scv[r];
        }
      }
      float pv[4][4];
#pragma unroll
      for (int r = 0; r < 4; ++r) {
        const float p0 = fexp2(sv[r][0] - Mr[r]);
        const float p1 = fexp2(sv[r][1] - Mr[r]);
        const float p2 = fexp2(sv[r][2] - Mr[r]);
        const float p3 = fexp2(sv[r][3] - Mr[r]);
        Lp[r] += (p0 + p1) + (p2 + p3);
        pv[r][0] = p0; pv[r][1] = p1; pv[r][2] = p2; pv[r][3] = p3;
      }

      // P -> per-wave LDS, stride 64, XOR-chunk swizzle; then PV
      unsigned short* pw = Ps + w * (16 * 64);
#pragma unroll
      for (int r = 0; r < 4; ++r) {
        const int prow = 4 * lh + r;
#pragma unroll
        for (int ct = 0; ct < 4; ++ct)
          pw[prow * 64 + (((ct * 2 + (lr >> 3)) ^ (prow & 7)) << 3) + (lr & 7)] =
              f2bf(pv[r][ct]);
      }
      asm volatile("s_waitcnt lgkmcnt(0)" ::: "memory");
      short8 pf[2];
      pf[0] = *(const short8*)((const char*)pw + lr * 128 + (((lh) ^ (lr & 7)) << 4));
      pf[1] = *(const short8*)((const char*)pw + lr * 128 + (((4 + lh) ^ (lr & 7)) << 4));
      __builtin_amdgcn_s_setprio(1);
#pragma unroll
      for (int vt = 0; vt < 8; ++vt) {
        const int d = vt * 16 + lr;
#pragma unroll
        for (int kb = 0; kb < 2; ++kb) {
          const short8 vf = *(const short8*)((const char*)Vt + d * 128 +
                                             (((kb * 4 + lh) ^ (lr & 7)) * 16));
          oacc[vt] = mfma16(pf[kb], vf, oacc[vt]);
        }
      }
      __builtin_amdgcn_s_setprio(0);
    }
    cur ^= 1;
  }

  // epilogue: reduce deferred L partials, normalize, store
#pragma unroll
  for (int r = 0; r < 4; ++r) {
    float Ls = Lp[r];
    Ls += __shfl_xor(Ls, 1, 16);
    Ls += __shfl_xor(Ls, 2, 16);
    Ls += __shfl_xor(Ls, 4, 16);
    Ls += __shfl_xor(Ls, 8, 16);
    const float inv = 1.0f / Ls;
    const size_t rowoff = (size_t)(q0 + wl * 16 + 4 * lh + r) * DMODEL + head * 128;
#pragma unroll
    for (int vt = 0; vt < 8; ++vt)
      aout[rowoff + vt * 16 + lr] = f2bf(oacc[vt][r] * inv);
  }
}

extern "C" void kernel_launch(void* const* d_in, const int* in_sizes, int n_in,
                              void* d_out, int out_size, void* d_ws, size_t ws_size,
                              hipStream_t stream) {
  (void)in_sizes; (void)n_in; (void)out_size; (void)ws_size;
  const float* x     = (const float*)d_in[0];
  const float* r_cos = (const float*)d_in[1];
  const float* r_sin = (const float*)d_in[2];
  const float* wnorm = (const float*)d_in[3];
  const float* wq    = (const float*)d_in[4];
  const float* wk    = (const float*)d_in[5];
  const float* wv    = (const float*)d_in[6];
  const float* wo    = (const float*)d_in[7];

  // ws layout (bf16 elems): bufA 8.39M | qkvb 10.49M | wT 25.17M | vtg 2.10M = 92.3MB
  unsigned short* bufA = (unsigned short*)d_ws;                  // h, later attn-out
  unsigned short* qkvb = bufA + (size_t)TOK * DMODEL;            // [2048][5120]
  unsigned short* wT   = qkvb + (size_t)TOK * QKV_LD;            // wqkv^T, later wo^T
  unsigned short* vtg  = wT + (size_t)6144 * DMODEL;             // V^T [1024][2048]

  // dynamic-LDS caps (idempotent, host-side; safe under graph capture)
  hipFuncSetAttribute((const void*)k_gemm_big<128, 192, 0>,
                      hipFuncAttributeMaxDynamicSharedMemorySize, 4 * (128 + 192) * 64);
  hipFuncSetAttribute((const void*)k_gemm_big<128, 128, 1>,
                      hipFuncAttributeMaxDynamicSharedMemorySize, 4 * (128 + 128) * 64);
  const int attn_lds = (4 * KVB * 128 + 8 * 16 * 64) * 2;        // 81920 B -> 2 blocks/CU
  hipFuncSetAttribute((const void*)k_attn,
                      hipFuncAttributeMaxDynamicSharedMemorySize, attn_lds);

  k_rmsnorm<<<TOK, 256, 0, stream>>>(x, wnorm, bufA);
  k_wconvert<<<dim3(64, 64), 256, 0, stream>>>(wq, wT, DMODEL, 4096);
  k_wconvert<<<dim3(16, 64), 256, 0, stream>>>(wk, wT + (size_t)4096 * DMODEL, DMODEL, 1024);
  k_wconvert<<<dim3(16, 64), 256, 0, stream>>>(wv, wT + (size_t)5120 * DMODEL, DMODEL, 1024);
  k_gemm_big<128, 192, 0><<<dim3(512), 512, 4 * (128 + 192) * 64, stream>>>(
      bufA, wT, nullptr, qkvb, vtg, r_cos, r_sin, TOK, 6144, DMODEL);
  k_wconvert<<<dim3(64, 64), 256, 0, stream>>>(wo, wT, DMODEL, 4096);   // overlay: wo^T
  k_attn<<<dim3(16, 32), 512, attn_lds, stream>>>(qkvb, vtg, bufA);
  k_gemm_big<128, 128, 1><<<dim3(512), 512, 4 * (128 + 128) * 64, stream>>>(
      bufA, wT, x, d_out, nullptr, nullptr, nullptr, TOK, DMODEL, DMODEL);
}

// Round 15
// 307.010 us; speedup vs baseline: 1.1940x; 1.1940x over previous
//
#include <hip/hip_runtime.h>
#include <stdint.h>
#include <math.h>

#define TOK 2048
#define DMODEL 4096
#define QKV_LD 5120   // q(4096) | k(1024); V goes transposed to vtg
#define KVB 64
#define PS_LD 72      // 64 kv + 8 pad (P-tile LDS stride)

typedef __attribute__((ext_vector_type(8))) short short8;
typedef __attribute__((ext_vector_type(4))) short short4v;
typedef __attribute__((ext_vector_type(8))) __bf16 bf16x8;
typedef __attribute__((ext_vector_type(4))) float f32x4;

__device__ __forceinline__ unsigned short f2bf(float f) {
  unsigned u = __float_as_uint(f);
  u += 0x7fffu + ((u >> 16) & 1u);   // RNE
  return (unsigned short)(u >> 16);
}

__device__ __forceinline__ void gl16(const void* g, void* l) {
  __builtin_amdgcn_global_load_lds((__attribute__((address_space(1))) void*)g,
                                   (__attribute__((address_space(3))) void*)l,
                                   16, 0, 0);
}

__device__ __forceinline__ f32x4 mfma16(short8 a, short8 b, f32x4 c) {
  return __builtin_amdgcn_mfma_f32_16x16x32_bf16(__builtin_bit_cast(bf16x8, a),
                                                 __builtin_bit_cast(bf16x8, b),
                                                 c, 0, 0, 0);
}

__device__ __forceinline__ float fexp2(float x) {
  float r;
  asm("v_exp_f32 %0, %1" : "=v"(r) : "v"(x));
  return r;
}

template <int N>
__device__ __forceinline__ void waitvm() {
  if constexpr (N == 0) asm volatile("s_waitcnt vmcnt(0)" ::: "memory");
  else if constexpr (N == 3) asm volatile("s_waitcnt vmcnt(3)" ::: "memory");
  else if constexpr (N == 4) asm volatile("s_waitcnt vmcnt(4)" ::: "memory");
  else static_assert(N == 0 || N == 3 || N == 4, "add literal");
}

__device__ __forceinline__ void waitvm0() {
  asm volatile("s_waitcnt vmcnt(0)" ::: "memory");
}

// ---------------- RMSNorm: fp32 x -> bf16 h ----------------
__global__ __launch_bounds__(256) void k_rmsnorm(const float* __restrict__ x,
                                                 const float* __restrict__ w,
                                                 unsigned short* __restrict__ h) {
  const int row = blockIdx.x;
  const float* xr = x + (size_t)row * DMODEL;
  float4 v[4];
  float ss = 0.f;
#pragma unroll
  for (int i = 0; i < 4; ++i) {
    v[i] = *(const float4*)(xr + threadIdx.x * 4 + i * 1024);
    ss += v[i].x * v[i].x + v[i].y * v[i].y + v[i].z * v[i].z + v[i].w * v[i].w;
  }
#pragma unroll
  for (int m = 1; m < 64; m <<= 1) ss += __shfl_xor(ss, m, 64);
  __shared__ float ws4[4];
  if ((threadIdx.x & 63) == 0) ws4[threadIdx.x >> 6] = ss;
  __syncthreads();
  const float scale = rsqrtf((ws4[0] + ws4[1] + ws4[2] + ws4[3]) * (1.0f / DMODEL) + 1e-5f);
  unsigned short* hr = h + (size_t)row * DMODEL;
#pragma unroll
  for (int i = 0; i < 4; ++i) {
    int col = threadIdx.x * 4 + i * 1024;
    float4 wv = *(const float4*)(w + col);
    uint2 o;
    o.x = (unsigned)f2bf(v[i].x * scale * wv.x) | ((unsigned)f2bf(v[i].y * scale * wv.y) << 16);
    o.y = (unsigned)f2bf(v[i].z * scale * wv.z) | ((unsigned)f2bf(v[i].w * scale * wv.w) << 16);
    *(uint2*)(hr + col) = o;
  }
}

// ------- Weight convert+transpose core: W[K=4096][N] fp32 -> WT[N][K] bf16 -------
__device__ __forceinline__ void wconv_body(const float* __restrict__ W,
                                           unsigned short* __restrict__ WT,
                                           int N, int n0, int k0,
                                           unsigned short (*tile)[65]) {
  const int t = threadIdx.x;
  {
    const int r = t >> 2, c0 = (t & 3) * 16;
    const float* src = W + (size_t)(k0 + r) * N + n0 + c0;
#pragma unroll
    for (int i = 0; i < 4; ++i) {
      float4 f = *(const float4*)(src + i * 4);
      tile[r][c0 + i * 4 + 0] = f2bf(f.x);
      tile[r][c0 + i * 4 + 1] = f2bf(f.y);
      tile[r][c0 + i * 4 + 2] = f2bf(f.z);
      tile[r][c0 + i * 4 + 3] = f2bf(f.w);
    }
  }
  __syncthreads();
  {
    const int n = t >> 2, c0 = (t & 3) * 16;
    unsigned short* dst = WT + (size_t)(n0 + n) * DMODEL + k0 + c0;
    unsigned short v[16];
#pragma unroll
    for (int i = 0; i < 16; ++i) v[i] = tile[c0 + i][n];
    uint4 o0, o1;
    o0.x = v[0] | ((unsigned)v[1] << 16);  o0.y = v[2] | ((unsigned)v[3] << 16);
    o0.z = v[4] | ((unsigned)v[5] << 16);  o0.w = v[6] | ((unsigned)v[7] << 16);
    o1.x = v[8] | ((unsigned)v[9] << 16);  o1.y = v[10] | ((unsigned)v[11] << 16);
    o1.z = v[12] | ((unsigned)v[13] << 16); o1.w = v[14] | ((unsigned)v[15] << 16);
    *(uint4*)dst = o0;
    *(uint4*)(dst + 8) = o1;
  }
}

// single-weight convert (wo)
__global__ __launch_bounds__(256) void k_wconvert(const float* __restrict__ W,
                                                  unsigned short* __restrict__ WT,
                                                  int N) {
  __shared__ unsigned short tile[64][65];
  wconv_body(W, WT, N, blockIdx.x * 64, blockIdx.y * 64, tile);
}

// fused 3-weight convert: z=0 wq(N=4096), z=1 wk(N=1024), z=2 wv(N=1024)
__global__ __launch_bounds__(256) void k_wconvert3(const float* __restrict__ wq,
                                                   const float* __restrict__ wk,
                                                   const float* __restrict__ wv,
                                                   unsigned short* __restrict__ WT) {
  __shared__ unsigned short tile[64][65];
  const int z = blockIdx.z;
  const float* W = (z == 0) ? wq : (z == 1) ? wk : wv;
  const int N = (z == 0) ? 4096 : 1024;
  const int n0 = blockIdx.x * 64;
  if (n0 >= N) return;
  unsigned short* dst = WT + (size_t)((z == 0) ? 0 : (z == 1) ? 4096 : 5120) * DMODEL;
  wconv_body(W, dst, N, n0, blockIdx.y * 64, tile);
}

// ======== Counted 2-barrier GEMM (round-8 proven): A x BT -> C ========
// 8 waves (2M x 4N), BK=64, double-buffered LDS, XOR-swizzled tiles.
// Per K-tile: P0 {stage h0 -> vmcnt(H0) -> barrier -> reads -> MFMA},
// P1 {stage h1 || reads/MFMA}, P2 {reads/MFMA}, P3 {reads -> lgkmcnt(0)
// -> barrier -> MFMA}. Loads never drained mid-loop. LDS dest is LINEAR
// (slot = i*512+tid); the XOR swizzle lives in the pre-swizzled GLOBAL
// source + the swizzled ds_read (rule 21 — gl16 cannot scatter).
__device__ __forceinline__ short8 rdfrag(const unsigned short* buf, int row, int kc) {
  return *(const short8*)((const char*)buf + row * 128 + ((kc ^ (row & 7)) << 4));
}

template <int BM, int BN, int HALF>
__device__ __forceinline__ void stage_half(const unsigned short* __restrict__ A,
                                           const unsigned short* __restrict__ BT,
                                           unsigned short* __restrict__ buf,
                                           int m0, int n0, int K, int kt, int tid) {
  constexpr int LA = BM / 64, LB = BN / 64;
  constexpr int H0A = LA / 2, H0B = (LB + 1) / 2;
  constexpr int A0 = HALF ? H0A : 0, A1 = HALF ? LA : H0A;
  constexpr int B0 = HALF ? H0B : 0, B1 = HALF ? LB : H0B;
  unsigned short* bbuf = buf + BM * 64;
#pragma unroll
  for (int i = A0; i < A1; ++i) {
    const int s = i * 512 + tid, row = s >> 3, ch = s & 7;
    gl16(A + (size_t)(m0 + row) * K + kt + ((ch ^ (row & 7)) << 3), (char*)buf + s * 16);
  }
#pragma unroll
  for (int i = B0; i < B1; ++i) {
    const int s = i * 512 + tid, row = s >> 3, ch = s & 7;
    gl16(BT + (size_t)(n0 + row) * K + kt + ((ch ^ (row & 7)) << 3), (char*)bbuf + s * 16);
  }
}

// MODE=0: qkv epilogue with fused RoPE (cols<5120 -> roped bf16 qkvb;
//         cols>=5120 -> vtg transposed).  MODE=1: fp32 C = acc + resid.
// Panel grid is (8 m) x (32 n) for both GEMMs; each XCD owns a 4m x 8n chunk.
template <int BM, int BN, int MODE>
__global__ __launch_bounds__(512, 2) void k_gemm_big(const unsigned short* __restrict__ A,
                                                     const unsigned short* __restrict__ BT,
                                                     const float* __restrict__ resid,
                                                     void* __restrict__ Cout,
                                                     unsigned short* __restrict__ vtg,
                                                     const float* __restrict__ rc,
                                                     const float* __restrict__ rs,
                                                     int M, int N, int K) {
  extern __shared__ __align__(16) unsigned short lds[];
  constexpr int MREP = BM / 32;            // 8 (two halves of 4)
  constexpr int NREP = BN / 64;            // 3 (qkv) / 2 (out)
  constexpr int TILE = (BM + BN) * 64;
  constexpr int LA = BM / 64, LB = BN / 64;
  constexpr int H0 = LA / 2 + (LB + 1) / 2;   // loads issued in P0

  const int tid = threadIdx.x, lane = tid & 63;
  const int w = tid >> 6, wm = w >> 2, wn = w & 3;
  const int lr = lane & 15, lh = lane >> 4;

  // 2-D XCD chunking over the 8x32 panel grid (bijective)
  const int wg0 = blockIdx.x;
  const int xcd = wg0 & 7, l = wg0 >> 3;
  const int m0 = (((xcd >> 2) << 2) + (l >> 3)) * BM;
  const int n0 = (((xcd & 3) << 3) + (l & 7)) * BN;

  const f32x4 zf = {0.f, 0.f, 0.f, 0.f};
  f32x4 acc[MREP][NREP];
#pragma unroll
  for (int i = 0; i < MREP; ++i) {
#pragma unroll
    for (int j = 0; j < NREP; ++j) acc[i][j] = zf;
  }

  const int arow0 = wm * (BM / 2);
  const int brow0 = wn * (BN / 4);
  const int NT = K >> 6;
  int cur = 0;

  stage_half<BM, BN, 0>(A, BT, lds, m0, n0, K, 0, tid);
  stage_half<BM, BN, 1>(A, BT, lds, m0, n0, K, 0, tid);

  for (int t = 0; t < NT; ++t) {
    const unsigned short* abuf = lds + cur * TILE;
    const unsigned short* bbuf = abuf + BM * 64;
    unsigned short* nbuf = lds + (cur ^ 1) * TILE;
    const bool pre = (t + 1 < NT);
    const int ktn = (t + 1) << 6;

    short8 bfr[NREP], afr[4];
    // ---- P0: stage h0(t+1), counted wait for tile t, barrier, kk0 h0
    if (pre) {
      stage_half<BM, BN, 0>(A, BT, nbuf, m0, n0, K, ktn, tid);
      waitvm<H0>();
    } else {
      waitvm<0>();
    }
    __builtin_amdgcn_s_barrier();
#pragma unroll
    for (int nr = 0; nr < NREP; ++nr) bfr[nr] = rdfrag(bbuf, brow0 + nr * 16 + lr, lh);
#pragma unroll
    for (int mi = 0; mi < 4; ++mi) afr[mi] = rdfrag(abuf, arow0 + mi * 16 + lr, lh);
    __builtin_amdgcn_s_setprio(1);
#pragma unroll
    for (int mi = 0; mi < 4; ++mi) {
#pragma unroll
      for (int nr = 0; nr < NREP; ++nr)
        acc[mi][nr] = mfma16(afr[mi], bfr[nr], acc[mi][nr]);
    }
    __builtin_amdgcn_s_setprio(0);
    // ---- P1: stage h1(t+1) || kk0 h1
    if (pre) stage_half<BM, BN, 1>(A, BT, nbuf, m0, n0, K, ktn, tid);
#pragma unroll
    for (int mi = 0; mi < 4; ++mi) afr[mi] = rdfrag(abuf, arow0 + (4 + mi) * 16 + lr, lh);
    __builtin_amdgcn_s_setprio(1);
#pragma unroll
    for (int mi = 0; mi < 4; ++mi) {
#pragma unroll
      for (int nr = 0; nr < NREP; ++nr)
        acc[4 + mi][nr] = mfma16(afr[mi], bfr[nr], acc[4 + mi][nr]);
    }
    __builtin_amdgcn_s_setprio(0);
    // ---- P2: kk1 h0
#pragma unroll
    for (int nr = 0; nr < NREP; ++nr) bfr[nr] = rdfrag(bbuf, brow0 + nr * 16 + lr, 4 + lh);
#pragma unroll
    for (int mi = 0; mi < 4; ++mi) afr[mi] = rdfrag(abuf, arow0 + mi * 16 + lr, 4 + lh);
    __builtin_amdgcn_s_setprio(1);
#pragma unroll
    for (int mi = 0; mi < 4; ++mi) {
#pragma unroll
      for (int nr = 0; nr < NREP; ++nr)
        acc[mi][nr] = mfma16(afr[mi], bfr[nr], acc[mi][nr]);
    }
    __builtin_amdgcn_s_setprio(0);
    // ---- P3: kk1 h1; all reads done -> barrier (frees buf[cur]) -> MFMA
#pragma unroll
    for (int mi = 0; mi < 4; ++mi) afr[mi] = rdfrag(abuf, arow0 + (4 + mi) * 16 + lr, 4 + lh);
    asm volatile("s_waitcnt lgkmcnt(0)" ::: "memory");
    __builtin_amdgcn_s_barrier();
    __builtin_amdgcn_s_setprio(1);
#pragma unroll
    for (int mi = 0; mi < 4; ++mi) {
#pragma unroll
      for (int nr = 0; nr < NREP; ++nr)
        acc[4 + mi][nr] = mfma16(afr[mi], bfr[nr], acc[4 + mi][nr]);
    }
    __builtin_amdgcn_s_setprio(0);
    cur ^= 1;
  }

  // ---- epilogue: C row = 4*lh + r, col = lr within each 16x16 tile
#pragma unroll
  for (int ai = 0; ai < MREP; ++ai) {
#pragma unroll
    for (int ni = 0; ni < NREP; ++ni) {
      const int colg = n0 + wn * (BN / 4) + ni * 16 + lr;
      const int rowg0 = m0 + wm * (BM / 2) + ai * 16 + 4 * lh;
      if (MODE == 1) {
#pragma unroll
        for (int r = 0; r < 4; ++r)
          ((float*)Cout)[(size_t)(rowg0 + r) * N + colg] =
              acc[ai][ni][r] + resid[(size_t)(rowg0 + r) * N + colg];
      } else if (colg >= 5120) {
        short4v o;
#pragma unroll
        for (int r = 0; r < 4; ++r) o[r] = (short)f2bf(acc[ai][ni][r]);
        *(short4v*)(vtg + (size_t)(colg - 5120) * TOK + rowg0) = o;
      } else {
        // fused RoPE: pair (even,odd) cols live in adjacent lanes
        const int d = colg & 127;
#pragma unroll
        for (int r = 0; r < 4; ++r) {
          const int row = rowg0 + r;
          const float v = acc[ai][ni][r];
          const float p = __shfl_xor(v, 1, 64);
          const float c = rc[row * 128 + d];
          const float s = rs[row * 128 + d];
          const float y = (lr & 1) ? fmaf(p, s, v * c) : fmaf(-p, s, v * c);
          ((unsigned short*)Cout)[(size_t)row * QKV_LD + colg] = f2bf(y);
        }
      }
    }
  }
}

// ---------------- Flash attention, causal, GQA (round-9 proven) ----------------
// grid (16 pairs, 32 heads); block = 4 waves x 16 q-rows = 64 q-rows.
// Single-barrier double-buffered K/V pipeline.
// Softmax: mask only diagonal tile; per-lane deferred L; defer-max skip (THR=8).
__global__ __launch_bounds__(256) void k_attn(const unsigned short* __restrict__ qkv,
                                              const unsigned short* __restrict__ vtg,
                                              unsigned short* __restrict__ aout) {
  extern __shared__ __align__(16) unsigned short sm[];
  unsigned short* const KsB = sm;                    // [2][KVB*128]
  unsigned short* const VtB = sm + 2 * KVB * 128;    // [2][128*KVB]
  unsigned short* const Ps = sm + 4 * KVB * 128;     // [4][16*PS_LD]
  const int head = blockIdx.y;
  const int hkv = head >> 2;
  const int tid = threadIdx.x, lane = tid & 63, w = tid >> 6;
  const int lr = lane & 15, lh = lane >> 4;
  const float scale2 = 0.08838834764831845f * 1.44269504088896340736f;  // /sqrt(128)*log2(e)
  const f32x4 zf = {0.f, 0.f, 0.f, 0.f};

  auto stageKV = [&](int kvt, int buf) {
    unsigned short* Ksn = KsB + buf * (KVB * 128);
    unsigned short* Vtn = VtB + buf * (128 * KVB);
    const int kvn = kvt * KVB;
#pragma unroll
    for (int c = 0; c < 4; ++c) {
      const int s = c * 256 + w * 64 + lane;
      const int row = s >> 4, cp = s & 15;
      gl16(qkv + (size_t)(kvn + row) * QKV_LD + 4096 + hkv * 128 + ((cp ^ (row & 7)) * 8),
           (char*)Ksn + (c * 256 + w * 64) * 16);
    }
#pragma unroll
    for (int c = 0; c < 4; ++c) {
      const int s = c * 256 + w * 64 + lane;
      const int row = s >> 3, cp = s & 7;
      gl16(vtg + (size_t)(hkv * 128 + row) * TOK + kvn + ((cp ^ (row & 7)) * 8),
           (char*)Vtn + (c * 256 + w * 64) * 16);
    }
  };

  for (int half = 0; half < 2; ++half) {
    const int qt = half ? (31 - blockIdx.x) : blockIdx.x;
    const int q0 = qt * 64;

    short8 qf[4];
    {
      const unsigned short* qbase = qkv + (size_t)(q0 + w * 16 + lr) * QKV_LD + head * 128;
#pragma unroll
      for (int kd = 0; kd < 4; ++kd) qf[kd] = *(const short8*)(qbase + kd * 32 + lh * 8);
    }
    f32x4 oacc[8];
#pragma unroll
    for (int vt = 0; vt < 8; ++vt) oacc[vt] = zf;
    float Mr[4], Lp[4];
#pragma unroll
    for (int r = 0; r < 4; ++r) { Mr[r] = -INFINITY; Lp[r] = 0.f; }

    const int nt = qt + 1;
    int cur = 0;
    stageKV(0, 0);    // prologue (buffer 0 free: inter-half barrier below)

    for (int t = 0; t < nt; ++t) {
      const unsigned short* Ks = KsB + cur * (KVB * 128);
      const unsigned short* Vt = VtB + cur * (128 * KVB);
      const int kv0 = t * KVB;
      waitvm0();
      __builtin_amdgcn_s_barrier();
      __builtin_amdgcn_sched_barrier(0);
      if (t + 1 < nt) stageKV(t + 1, cur ^ 1);

      // QK^T: S[16 q][64 kv] per wave
      f32x4 sacc[4];
#pragma unroll
      for (int ct = 0; ct < 4; ++ct) {
        sacc[ct] = zf;
        const int row = ct * 16 + lr;
#pragma unroll
        for (int kd = 0; kd < 4; ++kd) {
          const short8 kf = *(const short8*)((const char*)Ks + row * 256 +
                                             (((kd * 4 + lh) ^ (row & 7)) * 16));
          sacc[ct] = mfma16(qf[kd], kf, sacc[ct]);
        }
      }

      // softmax: scale, (diag-only) mask, max-reduce; defer-max skip; exp2
      const bool diag = (t == qt);
      float sv[4][4], gmax[4];
#pragma unroll
      for (int r = 0; r < 4; ++r) {
        float s0 = sacc[0][r] * scale2;
        float s1 = sacc[1][r] * scale2;
        float s2 = sacc[2][r] * scale2;
        float s3 = sacc[3][r] * scale2;
        if (diag) {
          const int qrow = q0 + w * 16 + 4 * lh + r;
          if (kv0 + lr > qrow) s0 = -INFINITY;
          if (kv0 + 16 + lr > qrow) s1 = -INFINITY;
          if (kv0 + 32 + lr > qrow) s2 = -INFINITY;
          if (kv0 + 48 + lr > qrow) s3 = -INFINITY;
        }
        float tmax = fmaxf(fmaxf(s0, s1), fmaxf(s2, s3));
        tmax = fmaxf(tmax, __shfl_xor(tmax, 1, 16));
        tmax = fmaxf(tmax, __shfl_xor(tmax, 2, 16));
        tmax = fmaxf(tmax, __shfl_xor(tmax, 4, 16));
        tmax = fmaxf(tmax, __shfl_xor(tmax, 8, 16));
        gmax[r] = tmax;
        sv[r][0] = s0; sv[r][1] = s1; sv[r][2] = s2; sv[r][3] = s3;
      }
      const int cond = (gmax[0] <= Mr[0] + 8.f) && (gmax[1] <= Mr[1] + 8.f) &&
                       (gmax[2] <= Mr[2] + 8.f) && (gmax[3] <= Mr[3] + 8.f);
      if (!__all(cond)) {
        float scv[4];
#pragma unroll
        for (int r = 0; r < 4; ++r) {
          const float mnew = fmaxf(Mr[r], gmax[r]);
          scv[r] = fexp2(Mr[r] - mnew);
          Mr[r] = mnew;
          Lp[r] *= scv[r];
        }
#pragma unroll
        for (int vt = 0; vt < 8; ++vt) {
#pragma unroll
          for (int r = 0; r < 4; ++r) oacc[vt][r] *= scv[r];
        }
      }
      float pv[4][4];
#pragma unroll
      for (int r = 0; r < 4; ++r) {
        const float p0 = fexp2(sv[r][0] - Mr[r]);
        const float p1 = fexp2(sv[r][1] - Mr[r]);
        const float p2 = fexp2(sv[r][2] - Mr[r]);
        const float p3 = fexp2(sv[r][3] - Mr[r]);
        Lp[r] += (p0 + p1) + (p2 + p3);   // per-lane partial; reduced at epilogue
        pv[r][0] = p0; pv[r][1] = p1; pv[r][2] = p2; pv[r][3] = p3;
      }

      // P -> per-wave LDS (stride 72 >= 64 kv), then PV
      unsigned short* pw = Ps + w * (16 * PS_LD);
#pragma unroll
      for (int r = 0; r < 4; ++r) {
#pragma unroll
        for (int ct = 0; ct < 4; ++ct)
          pw[(4 * lh + r) * PS_LD + ct * 16 + lr] = f2bf(pv[r][ct]);
      }
      asm volatile("s_waitcnt lgkmcnt(0)" ::: "memory");
      short8 pf[2];
      pf[0] = *(const short8*)(pw + lr * PS_LD + lh * 8);
      pf[1] = *(const short8*)(pw + lr * PS_LD + 32 + lh * 8);
      __builtin_amdgcn_s_setprio(1);
#pragma unroll
      for (int vt = 0; vt < 8; ++vt) {
        const int d = vt * 16 + lr;
#pragma unroll
        for (int kb = 0; kb < 2; ++kb) {
          const short8 vf = *(const short8*)((const char*)Vt + d * 128 +
                                             (((kb * 4 + lh) ^ (lr & 7)) * 16));
          oacc[vt] = mfma16(pf[kb], vf, oacc[vt]);
        }
      }
      __builtin_amdgcn_s_setprio(0);
      cur ^= 1;
    }

    // epilogue for this q-tile: reduce deferred L partials, normalize, store
#pragma unroll
    for (int r = 0; r < 4; ++r) {
      float Ls = Lp[r];
      Ls += __shfl_xor(Ls, 1, 16);
      Ls += __shfl_xor(Ls, 2, 16);
      Ls += __shfl_xor(Ls, 4, 16);
      Ls += __shfl_xor(Ls, 8, 16);
      const float inv = 1.0f / Ls;
      const size_t rowoff = (size_t)(q0 + w * 16 + 4 * lh + r) * DMODEL + head * 128;
#pragma unroll
      for (int vt = 0; vt < 8; ++vt)
        aout[rowoff + vt * 16 + lr] = f2bf(oacc[vt][r] * inv);
    }
    // inter-half barrier: next half's prologue overwrites buffer 0; all
    // waves' reads of this half must be retired (MFMA-consumed) first.
    __builtin_amdgcn_s_barrier();
    __builtin_amdgcn_sched_barrier(0);
  }
}

extern "C" void kernel_launch(void* const* d_in, const int* in_sizes, int n_in,
                              void* d_out, int out_size, void* d_ws, size_t ws_size,
                              hipStream_t stream) {
  (void)in_sizes; (void)n_in; (void)out_size; (void)ws_size;
  const float* x     = (const float*)d_in[0];
  const float* r_cos = (const float*)d_in[1];
  const float* r_sin = (const float*)d_in[2];
  const float* wnorm = (const float*)d_in[3];
  const float* wq    = (const float*)d_in[4];
  const float* wk    = (const float*)d_in[5];
  const float* wv    = (const float*)d_in[6];
  const float* wo    = (const float*)d_in[7];

  // ws layout (bf16 elems): bufA 8.39M | qkvb 10.49M | wT 25.17M | vtg 2.10M = 92.3MB
  unsigned short* bufA = (unsigned short*)d_ws;                  // h, later attn-out
  unsigned short* qkvb = bufA + (size_t)TOK * DMODEL;            // [2048][5120]
  unsigned short* wT   = qkvb + (size_t)TOK * QKV_LD;            // wqkv^T, later wo^T
  unsigned short* vtg  = wT + (size_t)6144 * DMODEL;             // V^T [1024][2048]

  // dynamic-LDS caps (idempotent, host-side; safe under graph capture)
  hipFuncSetAttribute((const void*)k_gemm_big<256, 192, 0>,
                      hipFuncAttributeMaxDynamicSharedMemorySize, 4 * (256 + 192) * 64);
  hipFuncSetAttribute((const void*)k_gemm_big<256, 128, 1>,
                      hipFuncAttributeMaxDynamicSharedMemorySize, 4 * (256 + 128) * 64);
  const int attn_lds = 4 * KVB * 128 * 2 + 4 * 16 * PS_LD * 2;   // 74752 B
  hipFuncSetAttribute((const void*)k_attn,
                      hipFuncAttributeMaxDynamicSharedMemorySize, attn_lds);

  k_rmsnorm<<<TOK, 256, 0, stream>>>(x, wnorm, bufA);
  k_wconvert3<<<dim3(64, 64, 3), 256, 0, stream>>>(wq, wk, wv, wT);
  k_gemm_big<256, 192, 0><<<dim3(256), 512, 4 * (256 + 192) * 64, stream>>>(
      bufA, wT, nullptr, qkvb, vtg, r_cos, r_sin, TOK, 6144, DMODEL);
  k_wconvert<<<dim3(64, 64), 256, 0, stream>>>(wo, wT, 4096);   // overlay: wo^T
  k_attn<<<dim3(16, 32), 256, attn_lds, stream>>>(qkvb, vtg, bufA);
  k_gemm_big<256, 128, 1><<<dim3(256), 512, 4 * (256 + 128) * 64, stream>>>(
      bufA, wT, x, d_out, nullptr, nullptr, nullptr, TOK, DMODEL, DMODEL);
}

// Round 16
// 306.203 us; speedup vs baseline: 1.1972x; 1.0026x over previous
//
#include <hip/hip_runtime.h>
#include <stdint.h>
#include <math.h>

#define TOK 2048
#define DMODEL 4096
#define QKV_LD 5120   // q(4096) | k(1024); V goes transposed to vtg
#define KVB 64
#define PS_LD 72      // 64 kv + 8 pad (P-tile LDS stride)

typedef __attribute__((ext_vector_type(8))) short short8;
typedef __attribute__((ext_vector_type(4))) short short4v;
typedef __attribute__((ext_vector_type(8))) __bf16 bf16x8;
typedef __attribute__((ext_vector_type(4))) float f32x4;

__device__ __forceinline__ unsigned short f2bf(float f) {
  unsigned u = __float_as_uint(f);
  u += 0x7fffu + ((u >> 16) & 1u);   // RNE
  return (unsigned short)(u >> 16);
}

__device__ __forceinline__ void gl16(const void* g, void* l) {
  __builtin_amdgcn_global_load_lds((__attribute__((address_space(1))) void*)g,
                                   (__attribute__((address_space(3))) void*)l,
                                   16, 0, 0);
}

__device__ __forceinline__ f32x4 mfma16(short8 a, short8 b, f32x4 c) {
  return __builtin_amdgcn_mfma_f32_16x16x32_bf16(__builtin_bit_cast(bf16x8, a),
                                                 __builtin_bit_cast(bf16x8, b),
                                                 c, 0, 0, 0);
}

__device__ __forceinline__ float fexp2(float x) {
  float r;
  asm("v_exp_f32 %0, %1" : "=v"(r) : "v"(x));
  return r;
}

template <int N>
__device__ __forceinline__ void waitvm() {
  if constexpr (N == 0) asm volatile("s_waitcnt vmcnt(0)" ::: "memory");
  else if constexpr (N == 3) asm volatile("s_waitcnt vmcnt(3)" ::: "memory");
  else if constexpr (N == 4) asm volatile("s_waitcnt vmcnt(4)" ::: "memory");
  else static_assert(N == 0 || N == 3 || N == 4, "add literal");
}

__device__ __forceinline__ void waitvm0() {
  asm volatile("s_waitcnt vmcnt(0)" ::: "memory");
}

// ---------------- RMSNorm: fp32 x -> bf16 h ----------------
__global__ __launch_bounds__(256) void k_rmsnorm(const float* __restrict__ x,
                                                 const float* __restrict__ w,
                                                 unsigned short* __restrict__ h) {
  const int row = blockIdx.x;
  const float* xr = x + (size_t)row * DMODEL;
  float4 v[4];
  float ss = 0.f;
#pragma unroll
  for (int i = 0; i < 4; ++i) {
    v[i] = *(const float4*)(xr + threadIdx.x * 4 + i * 1024);
    ss += v[i].x * v[i].x + v[i].y * v[i].y + v[i].z * v[i].z + v[i].w * v[i].w;
  }
#pragma unroll
  for (int m = 1; m < 64; m <<= 1) ss += __shfl_xor(ss, m, 64);
  __shared__ float ws4[4];
  if ((threadIdx.x & 63) == 0) ws4[threadIdx.x >> 6] = ss;
  __syncthreads();
  const float scale = rsqrtf((ws4[0] + ws4[1] + ws4[2] + ws4[3]) * (1.0f / DMODEL) + 1e-5f);
  unsigned short* hr = h + (size_t)row * DMODEL;
#pragma unroll
  for (int i = 0; i < 4; ++i) {
    int col = threadIdx.x * 4 + i * 1024;
    float4 wv = *(const float4*)(w + col);
    uint2 o;
    o.x = (unsigned)f2bf(v[i].x * scale * wv.x) | ((unsigned)f2bf(v[i].y * scale * wv.y) << 16);
    o.y = (unsigned)f2bf(v[i].z * scale * wv.z) | ((unsigned)f2bf(v[i].w * scale * wv.w) << 16);
    *(uint2*)(hr + col) = o;
  }
}

// ------- Weight convert+transpose core: W[K=4096][N] fp32 -> WT[N][K] bf16 -------
__device__ __forceinline__ void wconv_body(const float* __restrict__ W,
                                           unsigned short* __restrict__ WT,
                                           int N, int n0, int k0,
                                           unsigned short (*tile)[65]) {
  const int t = threadIdx.x;
  {
    const int r = t >> 2, c0 = (t & 3) * 16;
    const float* src = W + (size_t)(k0 + r) * N + n0 + c0;
#pragma unroll
    for (int i = 0; i < 4; ++i) {
      float4 f = *(const float4*)(src + i * 4);
      tile[r][c0 + i * 4 + 0] = f2bf(f.x);
      tile[r][c0 + i * 4 + 1] = f2bf(f.y);
      tile[r][c0 + i * 4 + 2] = f2bf(f.z);
      tile[r][c0 + i * 4 + 3] = f2bf(f.w);
    }
  }
  __syncthreads();
  {
    const int n = t >> 2, c0 = (t & 3) * 16;
    unsigned short* dst = WT + (size_t)(n0 + n) * DMODEL + k0 + c0;
    unsigned short v[16];
#pragma unroll
    for (int i = 0; i < 16; ++i) v[i] = tile[c0 + i][n];
    uint4 o0, o1;
    o0.x = v[0] | ((unsigned)v[1] << 16);  o0.y = v[2] | ((unsigned)v[3] << 16);
    o0.z = v[4] | ((unsigned)v[5] << 16);  o0.w = v[6] | ((unsigned)v[7] << 16);
    o1.x = v[8] | ((unsigned)v[9] << 16);  o1.y = v[10] | ((unsigned)v[11] << 16);
    o1.z = v[12] | ((unsigned)v[13] << 16); o1.w = v[14] | ((unsigned)v[15] << 16);
    *(uint4*)dst = o0;
    *(uint4*)(dst + 8) = o1;
  }
}

// single-weight convert (wo)
__global__ __launch_bounds__(256) void k_wconvert(const float* __restrict__ W,
                                                  unsigned short* __restrict__ WT,
                                                  int N) {
  __shared__ unsigned short tile[64][65];
  wconv_body(W, WT, N, blockIdx.x * 64, blockIdx.y * 64, tile);
}

// fused 3-weight convert: z=0 wq(N=4096), z=1 wk(N=1024), z=2 wv(N=1024)
__global__ __launch_bounds__(256) void k_wconvert3(const float* __restrict__ wq,
                                                   const float* __restrict__ wk,
                                                   const float* __restrict__ wv,
                                                   unsigned short* __restrict__ WT) {
  __shared__ unsigned short tile[64][65];
  const int z = blockIdx.z;
  const float* W = (z == 0) ? wq : (z == 1) ? wk : wv;
  const int N = (z == 0) ? 4096 : 1024;
  const int n0 = blockIdx.x * 64;
  if (n0 >= N) return;
  unsigned short* dst = WT + (size_t)((z == 0) ? 0 : (z == 1) ? 4096 : 5120) * DMODEL;
  wconv_body(W, dst, N, n0, blockIdx.y * 64, tile);
}

// ======== Counted 2-barrier GEMM (round-8 proven): A x BT -> C ========
__device__ __forceinline__ short8 rdfrag(const unsigned short* buf, int row, int kc) {
  return *(const short8*)((const char*)buf + row * 128 + ((kc ^ (row & 7)) << 4));
}

template <int BM, int BN, int HALF>
__device__ __forceinline__ void stage_half(const unsigned short* __restrict__ A,
                                           const unsigned short* __restrict__ BT,
                                           unsigned short* __restrict__ buf,
                                           int m0, int n0, int K, int kt, int tid) {
  constexpr int LA = BM / 64, LB = BN / 64;
  constexpr int H0A = LA / 2, H0B = (LB + 1) / 2;
  constexpr int A0 = HALF ? H0A : 0, A1 = HALF ? LA : H0A;
  constexpr int B0 = HALF ? H0B : 0, B1 = HALF ? LB : H0B;
  unsigned short* bbuf = buf + BM * 64;
#pragma unroll
  for (int i = A0; i < A1; ++i) {
    const int s = i * 512 + tid, row = s >> 3, ch = s & 7;
    gl16(A + (size_t)(m0 + row) * K + kt + ((ch ^ (row & 7)) << 3), (char*)buf + s * 16);
  }
#pragma unroll
  for (int i = B0; i < B1; ++i) {
    const int s = i * 512 + tid, row = s >> 3, ch = s & 7;
    gl16(BT + (size_t)(n0 + row) * K + kt + ((ch ^ (row & 7)) << 3), (char*)bbuf + s * 16);
  }
}

// MODE=0: qkv epilogue with fused RoPE (cols<5120 -> roped bf16 qkvb;
//         cols>=5120 -> vtg transposed).  MODE=1: fp32 C = acc + resid.
// Panel grid is (8 m) x (32 n) for both GEMMs; each XCD owns a 4m x 8n chunk.
template <int BM, int BN, int MODE>
__global__ __launch_bounds__(512, 2) void k_gemm_big(const unsigned short* __restrict__ A,
                                                     const unsigned short* __restrict__ BT,
                                                     const float* __restrict__ resid,
                                                     void* __restrict__ Cout,
                                                     unsigned short* __restrict__ vtg,
                                                     const float* __restrict__ rc,
                                                     const float* __restrict__ rs,
                                                     int M, int N, int K) {
  extern __shared__ __align__(16) unsigned short lds[];
  constexpr int MREP = BM / 32;            // 8 (two halves of 4)
  constexpr int NREP = BN / 64;            // 3 (qkv) / 2 (out)
  constexpr int TILE = (BM + BN) * 64;
  constexpr int LA = BM / 64, LB = BN / 64;
  constexpr int H0 = LA / 2 + (LB + 1) / 2;   // loads issued in P0

  const int tid = threadIdx.x, lane = tid & 63;
  const int w = tid >> 6, wm = w >> 2, wn = w & 3;
  const int lr = lane & 15, lh = lane >> 4;

  // 2-D XCD chunking over the 8x32 panel grid (bijective)
  const int wg0 = blockIdx.x;
  const int xcd = wg0 & 7, l = wg0 >> 3;
  const int m0 = (((xcd >> 2) << 2) + (l >> 3)) * BM;
  const int n0 = (((xcd & 3) << 3) + (l & 7)) * BN;

  const f32x4 zf = {0.f, 0.f, 0.f, 0.f};
  f32x4 acc[MREP][NREP];
#pragma unroll
  for (int i = 0; i < MREP; ++i) {
#pragma unroll
    for (int j = 0; j < NREP; ++j) acc[i][j] = zf;
  }

  const int arow0 = wm * (BM / 2);
  const int brow0 = wn * (BN / 4);
  const int NT = K >> 6;
  int cur = 0;

  stage_half<BM, BN, 0>(A, BT, lds, m0, n0, K, 0, tid);
  stage_half<BM, BN, 1>(A, BT, lds, m0, n0, K, 0, tid);

  for (int t = 0; t < NT; ++t) {
    const unsigned short* abuf = lds + cur * TILE;
    const unsigned short* bbuf = abuf + BM * 64;
    unsigned short* nbuf = lds + (cur ^ 1) * TILE;
    const bool pre = (t + 1 < NT);
    const int ktn = (t + 1) << 6;

    short8 bfr[NREP], afr[4];
    // ---- P0: stage h0(t+1), counted wait for tile t, barrier, kk0 h0
    if (pre) {
      stage_half<BM, BN, 0>(A, BT, nbuf, m0, n0, K, ktn, tid);
      waitvm<H0>();
    } else {
      waitvm<0>();
    }
    __builtin_amdgcn_s_barrier();
#pragma unroll
    for (int nr = 0; nr < NREP; ++nr) bfr[nr] = rdfrag(bbuf, brow0 + nr * 16 + lr, lh);
#pragma unroll
    for (int mi = 0; mi < 4; ++mi) afr[mi] = rdfrag(abuf, arow0 + mi * 16 + lr, lh);
    __builtin_amdgcn_s_setprio(1);
#pragma unroll
    for (int mi = 0; mi < 4; ++mi) {
#pragma unroll
      for (int nr = 0; nr < NREP; ++nr)
        acc[mi][nr] = mfma16(afr[mi], bfr[nr], acc[mi][nr]);
    }
    __builtin_amdgcn_s_setprio(0);
    // ---- P1: stage h1(t+1) || kk0 h1
    if (pre) stage_half<BM, BN, 1>(A, BT, nbuf, m0, n0, K, ktn, tid);
#pragma unroll
    for (int mi = 0; mi < 4; ++mi) afr[mi] = rdfrag(abuf, arow0 + (4 + mi) * 16 + lr, lh);
    __builtin_amdgcn_s_setprio(1);
#pragma unroll
    for (int mi = 0; mi < 4; ++mi) {
#pragma unroll
      for (int nr = 0; nr < NREP; ++nr)
        acc[4 + mi][nr] = mfma16(afr[mi], bfr[nr], acc[4 + mi][nr]);
    }
    __builtin_amdgcn_s_setprio(0);
    // ---- P2: kk1 h0
#pragma unroll
    for (int nr = 0; nr < NREP; ++nr) bfr[nr] = rdfrag(bbuf, brow0 + nr * 16 + lr, 4 + lh);
#pragma unroll
    for (int mi = 0; mi < 4; ++mi) afr[mi] = rdfrag(abuf, arow0 + mi * 16 + lr, 4 + lh);
    __builtin_amdgcn_s_setprio(1);
#pragma unroll
    for (int mi = 0; mi < 4; ++mi) {
#pragma unroll
      for (int nr = 0; nr < NREP; ++nr)
        acc[mi][nr] = mfma16(afr[mi], bfr[nr], acc[mi][nr]);
    }
    __builtin_amdgcn_s_setprio(0);
    // ---- P3: kk1 h1; all reads done -> barrier (frees buf[cur]) -> MFMA
#pragma unroll
    for (int mi = 0; mi < 4; ++mi) afr[mi] = rdfrag(abuf, arow0 + (4 + mi) * 16 + lr, 4 + lh);
    asm volatile("s_waitcnt lgkmcnt(0)" ::: "memory");
    __builtin_amdgcn_s_barrier();
    __builtin_amdgcn_s_setprio(1);
#pragma unroll
    for (int mi = 0; mi < 4; ++mi) {
#pragma unroll
      for (int nr = 0; nr < NREP; ++nr)
        acc[4 + mi][nr] = mfma16(afr[mi], bfr[nr], acc[4 + mi][nr]);
    }
    __builtin_amdgcn_s_setprio(0);
    cur ^= 1;
  }

  // ---- epilogue: C row = 4*lh + r, col = lr within each 16x16 tile
#pragma unroll
  for (int ai = 0; ai < MREP; ++ai) {
#pragma unroll
    for (int ni = 0; ni < NREP; ++ni) {
      const int colg = n0 + wn * (BN / 4) + ni * 16 + lr;
      const int rowg0 = m0 + wm * (BM / 2) + ai * 16 + 4 * lh;
      if (MODE == 1) {
#pragma unroll
        for (int r = 0; r < 4; ++r)
          ((float*)Cout)[(size_t)(rowg0 + r) * N + colg] =
              acc[ai][ni][r] + resid[(size_t)(rowg0 + r) * N + colg];
      } else if (colg >= 5120) {
        short4v o;
#pragma unroll
        for (int r = 0; r < 4; ++r) o[r] = (short)f2bf(acc[ai][ni][r]);
        *(short4v*)(vtg + (size_t)(colg - 5120) * TOK + rowg0) = o;
      } else {
        // fused RoPE: pair (even,odd) cols live in adjacent lanes
        const int d = colg & 127;
#pragma unroll
        for (int r = 0; r < 4; ++r) {
          const int row = rowg0 + r;
          const float v = acc[ai][ni][r];
          const float p = __shfl_xor(v, 1, 64);
          const float c = rc[row * 128 + d];
          const float s = rs[row * 128 + d];
          const float y = (lr & 1) ? fmaf(p, s, v * c) : fmaf(-p, s, v * c);
          ((unsigned short*)Cout)[(size_t)row * QKV_LD + colg] = f2bf(y);
        }
      }
    }
  }
}

// ---------------- Flash attention: QBLK=128, 8 waves, shared KV ----------------
// grid (8 pairs, 32 heads); 512 threads = 8 waves, each owning ONE 16-row strip
// of the same 128-row q-tile (no idle waves). Block does q-tile bx then 15-bx
// -> exactly 34 KV-tiles. Single-barrier double-buffered K/V pipeline; each
// staged KV tile serves 128 q-rows (2x the round-9 kernel). Per-wave math is
// byte-identical to the proven round-9 kernel. Softmax: mask only when
// t >= 2*qt (mask is a no-op for upper waves at t==2qt); per-lane deferred L;
// defer-max skip (THR=8).
__global__ __launch_bounds__(512) void k_attn(const unsigned short* __restrict__ qkv,
                                              const unsigned short* __restrict__ vtg,
                                              unsigned short* __restrict__ aout) {
  extern __shared__ __align__(16) unsigned short sm[];
  unsigned short* const KsB = sm;                    // [2][KVB*128]  32KB
  unsigned short* const VtB = sm + 2 * KVB * 128;    // [2][128*KVB]  32KB
  unsigned short* const Ps = sm + 4 * KVB * 128;     // [8][16*PS_LD] 18KB
  const int head = blockIdx.y;
  const int hkv = head >> 2;
  const int tid = threadIdx.x, lane = tid & 63, w = tid >> 6;
  const int lr = lane & 15, lh = lane >> 4;
  const float scale2 = 0.08838834764831845f * 1.44269504088896340736f;  // /sqrt(128)*log2(e)
  const f32x4 zf = {0.f, 0.f, 0.f, 0.f};

  auto stageKV = [&](int kvt, int buf) {
    unsigned short* Ksn = KsB + buf * (KVB * 128);
    unsigned short* Vtn = VtB + buf * (128 * KVB);
    const int kvn = kvt * KVB;
#pragma unroll
    for (int c = 0; c < 2; ++c) {
      const int s = c * 512 + tid;
      const int row = s >> 4, cp = s & 15;
      gl16(qkv + (size_t)(kvn + row) * QKV_LD + 4096 + hkv * 128 + ((cp ^ (row & 7)) * 8),
           (char*)Ksn + s * 16);
    }
#pragma unroll
    for (int c = 0; c < 2; ++c) {
      const int s = c * 512 + tid;
      const int row = s >> 3, cp = s & 7;
      gl16(vtg + (size_t)(hkv * 128 + row) * TOK + kvn + ((cp ^ (row & 7)) * 8),
           (char*)Vtn + s * 16);
    }
  };

  for (int half = 0; half < 2; ++half) {
    const int qt = half ? (15 - blockIdx.x) : blockIdx.x;   // 128-row q-tile
    const int q0 = qt * 128;

    short8 qf[4];
    {
      const unsigned short* qbase = qkv + (size_t)(q0 + w * 16 + lr) * QKV_LD + head * 128;
#pragma unroll
      for (int kd = 0; kd < 4; ++kd) qf[kd] = *(const short8*)(qbase + kd * 32 + lh * 8);
    }
    f32x4 oacc[8];
#pragma unroll
    for (int vt = 0; vt < 8; ++vt) oacc[vt] = zf;
    float Mr[4], Lp[4];
#pragma unroll
    for (int r = 0; r < 4; ++r) { Mr[r] = -INFINITY; Lp[r] = 0.f; }

    const int nt = 2 * qt + 2;
    const int ntw = 2 * qt + 1 + (w >> 2);   // wave-active bound: t <= 2qt + (w>>2)
    int cur = 0;
    stageKV(0, 0);    // prologue (buffer 0 free: inter-half barrier below)

    for (int t = 0; t < nt; ++t) {
      const unsigned short* Ks = KsB + cur * (KVB * 128);
      const unsigned short* Vt = VtB + cur * (128 * KVB);
      const int kv0 = t * KVB;
      waitvm0();
      __builtin_amdgcn_s_barrier();
      __builtin_amdgcn_sched_barrier(0);
      if (t + 1 < nt) stageKV(t + 1, cur ^ 1);

      if (t < ntw) {   // wave-uniform guard; barriers/staging stay outside
        // QK^T: S[16 q][64 kv] per wave
        f32x4 sacc[4];
#pragma unroll
        for (int ct = 0; ct < 4; ++ct) {
          sacc[ct] = zf;
          const int row = ct * 16 + lr;
#pragma unroll
          for (int kd = 0; kd < 4; ++kd) {
            const short8 kf = *(const short8*)((const char*)Ks + row * 256 +
                                               (((kd * 4 + lh) ^ (row & 7)) * 16));
            sacc[ct] = mfma16(qf[kd], kf, sacc[ct]);
          }
        }

        // softmax: scale, (near-diag) mask, max-reduce; defer-max skip; exp2
        const bool diag = (t >= 2 * qt);
        float sv[4][4], gmax[4];
#pragma unroll
        for (int r = 0; r < 4; ++r) {
          float s0 = sacc[0][r] * scale2;
          float s1 = sacc[1][r] * scale2;
          float s2 = sacc[2][r] * scale2;
          float s3 = sacc[3][r] * scale2;
          if (diag) {
            const int qrow = q0 + w * 16 + 4 * lh + r;
            if (kv0 + lr > qrow) s0 = -INFINITY;
            if (kv0 + 16 + lr > qrow) s1 = -INFINITY;
            if (kv0 + 32 + lr > qrow) s2 = -INFINITY;
            if (kv0 + 48 + lr > qrow) s3 = -INFINITY;
          }
          float tmax = fmaxf(fmaxf(s0, s1), fmaxf(s2, s3));
          tmax = fmaxf(tmax, __shfl_xor(tmax, 1, 16));
          tmax = fmaxf(tmax, __shfl_xor(tmax, 2, 16));
          tmax = fmaxf(tmax, __shfl_xor(tmax, 4, 16));
          tmax = fmaxf(tmax, __shfl_xor(tmax, 8, 16));
          gmax[r] = tmax;
          sv[r][0] = s0; sv[r][1] = s1; sv[r][2] = s2; sv[r][3] = s3;
        }
        const int cond = (gmax[0] <= Mr[0] + 8.f) && (gmax[1] <= Mr[1] + 8.f) &&
                         (gmax[2] <= Mr[2] + 8.f) && (gmax[3] <= Mr[3] + 8.f);
        if (!__all(cond)) {
          float scv[4];
#pragma unroll
          for (int r = 0; r < 4; ++r) {
            const float mnew = fmaxf(Mr[r], gmax[r]);
            scv[r] = fexp2(Mr[r] - mnew);
            Mr[r] = mnew;
            Lp[r] *= scv[r];
          }
#pragma unroll
          for (int vt = 0; vt < 8; ++vt) {
#pragma unroll
            for (int r = 0; r < 4; ++r) oacc[vt][r] *= scv[r];
          }
        }
        float pv[4][4];
#pragma unroll
        for (int r = 0; r < 4; ++r) {
          const float p0 = fexp2(sv[r][0] - Mr[r]);
          const float p1 = fexp2(sv[r][1] - Mr[r]);
          const float p2 = fexp2(sv[r][2] - Mr[r]);
          const float p3 = fexp2(sv[r][3] - Mr[r]);
          Lp[r] += (p0 + p1) + (p2 + p3);   // per-lane partial; reduced at epilogue
          pv[r][0] = p0; pv[r][1] = p1; pv[r][2] = p2; pv[r][3] = p3;
        }

        // P -> per-wave LDS (stride 72 >= 64 kv), then PV
        unsigned short* pw = Ps + w * (16 * PS_LD);
#pragma unroll
        for (int r = 0; r < 4; ++r) {
#pragma unroll
          for (int ct = 0; ct < 4; ++ct)
            pw[(4 * lh + r) * PS_LD + ct * 16 + lr] = f2bf(pv[r][ct]);
        }
        asm volatile("s_waitcnt lgkmcnt(0)" ::: "memory");
        short8 pf[2];
        pf[0] = *(const short8*)(pw + lr * PS_LD + lh * 8);
        pf[1] = *(const short8*)(pw + lr * PS_LD + 32 + lh * 8);
        __builtin_amdgcn_s_setprio(1);
#pragma unroll
        for (int vt = 0; vt < 8; ++vt) {
          const int d = vt * 16 + lr;
#pragma unroll
          for (int kb = 0; kb < 2; ++kb) {
            const short8 vf = *(const short8*)((const char*)Vt + d * 128 +
                                               (((kb * 4 + lh) ^ (lr & 7)) * 16));
            oacc[vt] = mfma16(pf[kb], vf, oacc[vt]);
          }
        }
        __builtin_amdgcn_s_setprio(0);
      }
      cur ^= 1;
    }

    // epilogue for this q-tile: reduce deferred L partials, normalize, store
#pragma unroll
    for (int r = 0; r < 4; ++r) {
      float Ls = Lp[r];
      Ls += __shfl_xor(Ls, 1, 16);
      Ls += __shfl_xor(Ls, 2, 16);
      Ls += __shfl_xor(Ls, 4, 16);
      Ls += __shfl_xor(Ls, 8, 16);
      const float inv = 1.0f / Ls;
      const size_t rowoff = (size_t)(q0 + w * 16 + 4 * lh + r) * DMODEL + head * 128;
#pragma unroll
      for (int vt = 0; vt < 8; ++vt)
        aout[rowoff + vt * 16 + lr] = f2bf(oacc[vt][r] * inv);
    }
    // inter-half barrier: next half's prologue overwrites buffer 0; all
    // waves' reads of this half must be retired (MFMA-consumed) first.
    __builtin_amdgcn_s_barrier();
    __builtin_amdgcn_sched_barrier(0);
  }
}

extern "C" void kernel_launch(void* const* d_in, const int* in_sizes, int n_in,
                              void* d_out, int out_size, void* d_ws, size_t ws_size,
                              hipStream_t stream) {
  (void)in_sizes; (void)n_in; (void)out_size; (void)ws_size;
  const float* x     = (const float*)d_in[0];
  const float* r_cos = (const float*)d_in[1];
  const float* r_sin = (const float*)d_in[2];
  const float* wnorm = (const float*)d_in[3];
  const float* wq    = (const float*)d_in[4];
  const float* wk    = (const float*)d_in[5];
  const float* wv    = (const float*)d_in[6];
  const float* wo    = (const float*)d_in[7];

  // ws layout (bf16 elems): bufA 8.39M | qkvb 10.49M | wT 25.17M | vtg 2.10M = 92.3MB
  unsigned short* bufA = (unsigned short*)d_ws;                  // h, later attn-out
  unsigned short* qkvb = bufA + (size_t)TOK * DMODEL;            // [2048][5120]
  unsigned short* wT   = qkvb + (size_t)TOK * QKV_LD;            // wqkv^T, later wo^T
  unsigned short* vtg  = wT + (size_t)6144 * DMODEL;             // V^T [1024][2048]

  // dynamic-LDS caps (idempotent, host-side; safe under graph capture)
  hipFuncSetAttribute((const void*)k_gemm_big<256, 192, 0>,
                      hipFuncAttributeMaxDynamicSharedMemorySize, 4 * (256 + 192) * 64);
  hipFuncSetAttribute((const void*)k_gemm_big<256, 128, 1>,
                      hipFuncAttributeMaxDynamicSharedMemorySize, 4 * (256 + 128) * 64);
  const int attn_lds = 4 * KVB * 128 * 2 + 8 * 16 * PS_LD * 2;   // 83968 B
  hipFuncSetAttribute((const void*)k_attn,
                      hipFuncAttributeMaxDynamicSharedMemorySize, attn_lds);

  k_rmsnorm<<<TOK, 256, 0, stream>>>(x, wnorm, bufA);
  k_wconvert3<<<dim3(64, 64, 3), 256, 0, stream>>>(wq, wk, wv, wT);
  k_gemm_big<256, 192, 0><<<dim3(256), 512, 4 * (256 + 192) * 64, stream>>>(
      bufA, wT, nullptr, qkvb, vtg, r_cos, r_sin, TOK, 6144, DMODEL);
  k_wconvert<<<dim3(64, 64), 256, 0, stream>>>(wo, wT, 4096);   // overlay: wo^T
  k_attn<<<dim3(8, 32), 512, attn_lds, stream>>>(qkvb, vtg, bufA);
  k_gemm_big<256, 128, 1><<<dim3(256), 512, 4 * (256 + 128) * 64, stream>>>(
      bufA, wT, x, d_out, nullptr, nullptr, nullptr, TOK, DMODEL, DMODEL);
}

// Round 17
// 294.876 us; speedup vs baseline: 1.2432x; 1.0384x over previous
//
#include <hip/hip_runtime.h>
#include <stdint.h>
#include <math.h>

#define TOK 2048
#define DMODEL 4096
#define QKV_LD 5120   // q(4096) | k(1024); V goes transposed to vtg
#define KVB 64
#define PSTR 40       // P slot stride bytes (8 dwords + pad, 8B aligned)

typedef __attribute__((ext_vector_type(8))) short short8;
typedef __attribute__((ext_vector_type(4))) short short4v;
typedef __attribute__((ext_vector_type(8))) __bf16 bf16x8;
typedef __attribute__((ext_vector_type(4))) float f32x4;

__device__ __forceinline__ unsigned short f2bf(float f) {
  unsigned u = __float_as_uint(f);
  u += 0x7fffu + ((u >> 16) & 1u);   // RNE
  return (unsigned short)(u >> 16);
}

__device__ __forceinline__ unsigned pk2bf(float a, float b) {
  return (unsigned)f2bf(a) | ((unsigned)f2bf(b) << 16);
}

__device__ __forceinline__ void gl16(const void* g, void* l) {
  __builtin_amdgcn_global_load_lds((__attribute__((address_space(1))) void*)g,
                                   (__attribute__((address_space(3))) void*)l,
                                   16, 0, 0);
}

__device__ __forceinline__ f32x4 mfma16(short8 a, short8 b, f32x4 c) {
  return __builtin_amdgcn_mfma_f32_16x16x32_bf16(__builtin_bit_cast(bf16x8, a),
                                                 __builtin_bit_cast(bf16x8, b),
                                                 c, 0, 0, 0);
}

__device__ __forceinline__ float fexp2(float x) {
  float r;
  asm("v_exp_f32 %0, %1" : "=v"(r) : "v"(x));
  return r;
}

template <int N>
__device__ __forceinline__ void waitvm() {
  if constexpr (N == 0) asm volatile("s_waitcnt vmcnt(0)" ::: "memory");
  else if constexpr (N == 3) asm volatile("s_waitcnt vmcnt(3)" ::: "memory");
  else if constexpr (N == 4) asm volatile("s_waitcnt vmcnt(4)" ::: "memory");
  else static_assert(N == 0 || N == 3 || N == 4, "add literal");
}

__device__ __forceinline__ void waitvm0() {
  asm volatile("s_waitcnt vmcnt(0)" ::: "memory");
}

// ---------------- RMSNorm: fp32 x -> bf16 h ----------------
__global__ __launch_bounds__(256) void k_rmsnorm(const float* __restrict__ x,
                                                 const float* __restrict__ w,
                                                 unsigned short* __restrict__ h) {
  const int row = blockIdx.x;
  const float* xr = x + (size_t)row * DMODEL;
  float4 v[4];
  float ss = 0.f;
#pragma unroll
  for (int i = 0; i < 4; ++i) {
    v[i] = *(const float4*)(xr + threadIdx.x * 4 + i * 1024);
    ss += v[i].x * v[i].x + v[i].y * v[i].y + v[i].z * v[i].z + v[i].w * v[i].w;
  }
#pragma unroll
  for (int m = 1; m < 64; m <<= 1) ss += __shfl_xor(ss, m, 64);
  __shared__ float ws4[4];
  if ((threadIdx.x & 63) == 0) ws4[threadIdx.x >> 6] = ss;
  __syncthreads();
  const float scale = rsqrtf((ws4[0] + ws4[1] + ws4[2] + ws4[3]) * (1.0f / DMODEL) + 1e-5f);
  unsigned short* hr = h + (size_t)row * DMODEL;
#pragma unroll
  for (int i = 0; i < 4; ++i) {
    int col = threadIdx.x * 4 + i * 1024;
    float4 wv = *(const float4*)(w + col);
    uint2 o;
    o.x = (unsigned)f2bf(v[i].x * scale * wv.x) | ((unsigned)f2bf(v[i].y * scale * wv.y) << 16);
    o.y = (unsigned)f2bf(v[i].z * scale * wv.z) | ((unsigned)f2bf(v[i].w * scale * wv.w) << 16);
    *(uint2*)(hr + col) = o;
  }
}

// ------- Weight convert+transpose core: W[K=4096][N] fp32 -> WT[N][K] bf16 -------
__device__ __forceinline__ void wconv_body(const float* __restrict__ W,
                                           unsigned short* __restrict__ WT,
                                           int N, int n0, int k0,
                                           unsigned short (*tile)[65]) {
  const int t = threadIdx.x;
  {
    const int r = t >> 2, c0 = (t & 3) * 16;
    const float* src = W + (size_t)(k0 + r) * N + n0 + c0;
#pragma unroll
    for (int i = 0; i < 4; ++i) {
      float4 f = *(const float4*)(src + i * 4);
      tile[r][c0 + i * 4 + 0] = f2bf(f.x);
      tile[r][c0 + i * 4 + 1] = f2bf(f.y);
      tile[r][c0 + i * 4 + 2] = f2bf(f.z);
      tile[r][c0 + i * 4 + 3] = f2bf(f.w);
    }
  }
  __syncthreads();
  {
    const int n = t >> 2, c0 = (t & 3) * 16;
    unsigned short* dst = WT + (size_t)(n0 + n) * DMODEL + k0 + c0;
    unsigned short v[16];
#pragma unroll
    for (int i = 0; i < 16; ++i) v[i] = tile[c0 + i][n];
    uint4 o0, o1;
    o0.x = v[0] | ((unsigned)v[1] << 16);  o0.y = v[2] | ((unsigned)v[3] << 16);
    o0.z = v[4] | ((unsigned)v[5] << 16);  o0.w = v[6] | ((unsigned)v[7] << 16);
    o1.x = v[8] | ((unsigned)v[9] << 16);  o1.y = v[10] | ((unsigned)v[11] << 16);
    o1.z = v[12] | ((unsigned)v[13] << 16); o1.w = v[14] | ((unsigned)v[15] << 16);
    *(uint4*)dst = o0;
    *(uint4*)(dst + 8) = o1;
  }
}

// single-weight convert (wo)
__global__ __launch_bounds__(256) void k_wconvert(const float* __restrict__ W,
                                                  unsigned short* __restrict__ WT,
                                                  int N) {
  __shared__ unsigned short tile[64][65];
  wconv_body(W, WT, N, blockIdx.x * 64, blockIdx.y * 64, tile);
}

// fused 3-weight convert: z=0 wq(N=4096), z=1 wk(N=1024), z=2 wv(N=1024)
__global__ __launch_bounds__(256) void k_wconvert3(const float* __restrict__ wq,
                                                   const float* __restrict__ wk,
                                                   const float* __restrict__ wv,
                                                   unsigned short* __restrict__ WT) {
  __shared__ unsigned short tile[64][65];
  const int z = blockIdx.z;
  const float* W = (z == 0) ? wq : (z == 1) ? wk : wv;
  const int N = (z == 0) ? 4096 : 1024;
  const int n0 = blockIdx.x * 64;
  if (n0 >= N) return;
  unsigned short* dst = WT + (size_t)((z == 0) ? 0 : (z == 1) ? 4096 : 5120) * DMODEL;
  wconv_body(W, dst, N, n0, blockIdx.y * 64, tile);
}

// ======== Counted 2-barrier GEMM (round-8 proven): A x BT -> C ========
__device__ __forceinline__ short8 rdfrag(const unsigned short* buf, int row, int kc) {
  return *(const short8*)((const char*)buf + row * 128 + ((kc ^ (row & 7)) << 4));
}

template <int BM, int BN, int HALF>
__device__ __forceinline__ void stage_half(const unsigned short* __restrict__ A,
                                           const unsigned short* __restrict__ BT,
                                           unsigned short* __restrict__ buf,
                                           int m0, int n0, int K, int kt, int tid) {
  constexpr int LA = BM / 64, LB = BN / 64;
  constexpr int H0A = LA / 2, H0B = (LB + 1) / 2;
  constexpr int A0 = HALF ? H0A : 0, A1 = HALF ? LA : H0A;
  constexpr int B0 = HALF ? H0B : 0, B1 = HALF ? LB : H0B;
  unsigned short* bbuf = buf + BM * 64;
#pragma unroll
  for (int i = A0; i < A1; ++i) {
    const int s = i * 512 + tid, row = s >> 3, ch = s & 7;
    gl16(A + (size_t)(m0 + row) * K + kt + ((ch ^ (row & 7)) << 3), (char*)buf + s * 16);
  }
#pragma unroll
  for (int i = B0; i < B1; ++i) {
    const int s = i * 512 + tid, row = s >> 3, ch = s & 7;
    gl16(BT + (size_t)(n0 + row) * K + kt + ((ch ^ (row & 7)) << 3), (char*)bbuf + s * 16);
  }
}

// MODE=0: qkv epilogue with fused RoPE (cols<5120 -> roped bf16 qkvb;
//         cols>=5120 -> vtg transposed).  MODE=1: fp32 C = acc + resid.
// Panel grid is (8 m) x (32 n) for both GEMMs; each XCD owns a 4m x 8n chunk.
template <int BM, int BN, int MODE>
__global__ __launch_bounds__(512, 2) void k_gemm_big(const unsigned short* __restrict__ A,
                                                     const unsigned short* __restrict__ BT,
                                                     const float* __restrict__ resid,
                                                     void* __restrict__ Cout,
                                                     unsigned short* __restrict__ vtg,
                                                     const float* __restrict__ rc,
                                                     const float* __restrict__ rs,
                                                     int M, int N, int K) {
  extern __shared__ __align__(16) unsigned short lds[];
  constexpr int MREP = BM / 32;            // 8 (two halves of 4)
  constexpr int NREP = BN / 64;            // 3 (qkv) / 2 (out)
  constexpr int TILE = (BM + BN) * 64;
  constexpr int LA = BM / 64, LB = BN / 64;
  constexpr int H0 = LA / 2 + (LB + 1) / 2;   // loads issued in P0

  const int tid = threadIdx.x, lane = tid & 63;
  const int w = tid >> 6, wm = w >> 2, wn = w & 3;
  const int lr = lane & 15, lh = lane >> 4;

  // 2-D XCD chunking over the 8x32 panel grid (bijective)
  const int wg0 = blockIdx.x;
  const int xcd = wg0 & 7, l = wg0 >> 3;
  const int m0 = (((xcd >> 2) << 2) + (l >> 3)) * BM;
  const int n0 = (((xcd & 3) << 3) + (l & 7)) * BN;

  const f32x4 zf = {0.f, 0.f, 0.f, 0.f};
  f32x4 acc[MREP][NREP];
#pragma unroll
  for (int i = 0; i < MREP; ++i) {
#pragma unroll
    for (int j = 0; j < NREP; ++j) acc[i][j] = zf;
  }

  const int arow0 = wm * (BM / 2);
  const int brow0 = wn * (BN / 4);
  const int NT = K >> 6;
  int cur = 0;

  stage_half<BM, BN, 0>(A, BT, lds, m0, n0, K, 0, tid);
  stage_half<BM, BN, 1>(A, BT, lds, m0, n0, K, 0, tid);

  for (int t = 0; t < NT; ++t) {
    const unsigned short* abuf = lds + cur * TILE;
    const unsigned short* bbuf = abuf + BM * 64;
    unsigned short* nbuf = lds + (cur ^ 1) * TILE;
    const bool pre = (t + 1 < NT);
    const int ktn = (t + 1) << 6;

    short8 bfr[NREP], afr[4];
    // ---- P0: stage h0(t+1), counted wait for tile t, barrier, kk0 h0
    if (pre) {
      stage_half<BM, BN, 0>(A, BT, nbuf, m0, n0, K, ktn, tid);
      waitvm<H0>();
    } else {
      waitvm<0>();
    }
    __builtin_amdgcn_s_barrier();
#pragma unroll
    for (int nr = 0; nr < NREP; ++nr) bfr[nr] = rdfrag(bbuf, brow0 + nr * 16 + lr, lh);
#pragma unroll
    for (int mi = 0; mi < 4; ++mi) afr[mi] = rdfrag(abuf, arow0 + mi * 16 + lr, lh);
    __builtin_amdgcn_s_setprio(1);
#pragma unroll
    for (int mi = 0; mi < 4; ++mi) {
#pragma unroll
      for (int nr = 0; nr < NREP; ++nr)
        acc[mi][nr] = mfma16(afr[mi], bfr[nr], acc[mi][nr]);
    }
    __builtin_amdgcn_s_setprio(0);
    // ---- P1: stage h1(t+1) || kk0 h1
    if (pre) stage_half<BM, BN, 1>(A, BT, nbuf, m0, n0, K, ktn, tid);
#pragma unroll
    for (int mi = 0; mi < 4; ++mi) afr[mi] = rdfrag(abuf, arow0 + (4 + mi) * 16 + lr, lh);
    __builtin_amdgcn_s_setprio(1);
#pragma unroll
    for (int mi = 0; mi < 4; ++mi) {
#pragma unroll
      for (int nr = 0; nr < NREP; ++nr)
        acc[4 + mi][nr] = mfma16(afr[mi], bfr[nr], acc[4 + mi][nr]);
    }
    __builtin_amdgcn_s_setprio(0);
    // ---- P2: kk1 h0
#pragma unroll
    for (int nr = 0; nr < NREP; ++nr) bfr[nr] = rdfrag(bbuf, brow0 + nr * 16 + lr, 4 + lh);
#pragma unroll
    for (int mi = 0; mi < 4; ++mi) afr[mi] = rdfrag(abuf, arow0 + mi * 16 + lr, 4 + lh);
    __builtin_amdgcn_s_setprio(1);
#pragma unroll
    for (int mi = 0; mi < 4; ++mi) {
#pragma unroll
      for (int nr = 0; nr < NREP; ++nr)
        acc[mi][nr] = mfma16(afr[mi], bfr[nr], acc[mi][nr]);
    }
    __builtin_amdgcn_s_setprio(0);
    // ---- P3: kk1 h1; all reads done -> barrier (frees buf[cur]) -> MFMA
#pragma unroll
    for (int mi = 0; mi < 4; ++mi) afr[mi] = rdfrag(abuf, arow0 + (4 + mi) * 16 + lr, 4 + lh);
    asm volatile("s_waitcnt lgkmcnt(0)" ::: "memory");
    __builtin_amdgcn_s_barrier();
    __builtin_amdgcn_s_setprio(1);
#pragma unroll
    for (int mi = 0; mi < 4; ++mi) {
#pragma unroll
      for (int nr = 0; nr < NREP; ++nr)
        acc[4 + mi][nr] = mfma16(afr[mi], bfr[nr], acc[4 + mi][nr]);
    }
    __builtin_amdgcn_s_setprio(0);
    cur ^= 1;
  }

  // ---- epilogue: C row = 4*lh + r, col = lr within each 16x16 tile
#pragma unroll
  for (int ai = 0; ai < MREP; ++ai) {
#pragma unroll
    for (int ni = 0; ni < NREP; ++ni) {
      const int colg = n0 + wn * (BN / 4) + ni * 16 + lr;
      const int rowg0 = m0 + wm * (BM / 2) + ai * 16 + 4 * lh;
      if (MODE == 1) {
#pragma unroll
        for (int r = 0; r < 4; ++r)
          ((float*)Cout)[(size_t)(rowg0 + r) * N + colg] =
              acc[ai][ni][r] + resid[(size_t)(rowg0 + r) * N + colg];
      } else if (colg >= 5120) {
        short4v o;
#pragma unroll
        for (int r = 0; r < 4; ++r) o[r] = (short)f2bf(acc[ai][ni][r]);
        *(short4v*)(vtg + (size_t)(colg - 5120) * TOK + rowg0) = o;
      } else {
        // fused RoPE: pair (even,odd) cols live in adjacent lanes
        const int d = colg & 127;
#pragma unroll
        for (int r = 0; r < 4; ++r) {
          const int row = rowg0 + r;
          const float v = acc[ai][ni][r];
          const float p = __shfl_xor(v, 1, 64);
          const float c = rc[row * 128 + d];
          const float s = rs[row * 128 + d];
          const float y = (lr & 1) ? fmaf(p, s, v * c) : fmaf(-p, s, v * c);
          ((unsigned short*)Cout)[(size_t)row * QKV_LD + colg] = f2bf(y);
        }
      }
    }
  }
}

// ---------------- Flash attention: swapped QK^T (q lane-local) ----------------
// grid (16 pairs, 32 heads); block = 4 waves x 16 q-rows = 64 q-rows.
// Single-barrier double-buffered K/V pipeline (round-9 proven).
// S = mfma(K, Q): lane (lr,lh) holds S[kv=ct*16+4lh+r][q=lr] -> softmax is
// lane-local in q (in-lane max/sum + 2 shfl over lh); Mr/Lp are scalars.
// P packed as 8 dwords/lane (kv-adjacent reg pairs), LDS roundtrip is
// 4x ds_write_b64 + 4x ds_read_b64 (stride 40B, 8B-aligned). PV = mfma(V^T,P):
// O[d=vt*16+4lh+r][q=lr]; epilogue packs short4 stores, L-reduce = 2 shfls.
__global__ __launch_bounds__(256) void k_attn(const unsigned short* __restrict__ qkv,
                                              const unsigned short* __restrict__ vtg,
                                              unsigned short* __restrict__ aout) {
  extern __shared__ __align__(16) unsigned short sm[];
  unsigned short* const KsB = sm;                    // [2][KVB*128] 32KB
  unsigned short* const VtB = sm + 2 * KVB * 128;    // [2][128*KVB] 32KB
  char* const Pb = (char*)(sm + 4 * KVB * 128);      // 256 lanes * 40B = 10KB
  const int head = blockIdx.y;
  const int hkv = head >> 2;
  const int tid = threadIdx.x, lane = tid & 63, w = tid >> 6;
  const int lr = lane & 15, lh = lane >> 4;
  const float scale2 = 0.08838834764831845f * 1.44269504088896340736f;  // /sqrt(128)*log2(e)
  const f32x4 zf = {0.f, 0.f, 0.f, 0.f};

  char* const myp = Pb + (size_t)tid * PSTR;           // own P slot
  const char* const pw0 = Pb + (size_t)(w * 64) * PSTR;  // wave's P base
  const int s1 = lr + 16 * (2 * (lh & 1));             // P source lanes
  const int s2 = s1 + 16;

  auto stageKV = [&](int kvt, int buf) {
    unsigned short* Ksn = KsB + buf * (KVB * 128);
    unsigned short* Vtn = VtB + buf * (128 * KVB);
    const int kvn = kvt * KVB;
#pragma unroll
    for (int c = 0; c < 4; ++c) {
      const int s = c * 256 + w * 64 + lane;
      const int row = s >> 4, cp = s & 15;
      gl16(qkv + (size_t)(kvn + row) * QKV_LD + 4096 + hkv * 128 + ((cp ^ (row & 7)) * 8),
           (char*)Ksn + (c * 256 + w * 64) * 16);
    }
#pragma unroll
    for (int c = 0; c < 4; ++c) {
      const int s = c * 256 + w * 64 + lane;
      const int row = s >> 3, cp = s & 7;
      gl16(vtg + (size_t)(hkv * 128 + row) * TOK + kvn + ((cp ^ (row & 7)) * 8),
           (char*)Vtn + (c * 256 + w * 64) * 16);
    }
  };

  for (int half = 0; half < 2; ++half) {
    const int qt = half ? (31 - blockIdx.x) : blockIdx.x;
    const int q0 = qt * 64;
    const int qrow = q0 + w * 16 + lr;   // this lane's q row

    short8 qf[4];
    {
      const unsigned short* qbase = qkv + (size_t)qrow * QKV_LD + head * 128;
#pragma unroll
      for (int kd = 0; kd < 4; ++kd) qf[kd] = *(const short8*)(qbase + kd * 32 + lh * 8);
    }
    f32x4 oacc[8];
#pragma unroll
    for (int vt = 0; vt < 8; ++vt) oacc[vt] = zf;
    float Mr = -INFINITY, Lp = 0.f;

    const int nt = qt + 1;
    int cur = 0;
    stageKV(0, 0);    // prologue (buffer 0 free: inter-half barrier below)

    for (int t = 0; t < nt; ++t) {
      const unsigned short* Ks = KsB + cur * (KVB * 128);
      const unsigned short* Vt = VtB + cur * (128 * KVB);
      const int kv0 = t * KVB;
      waitvm0();
      __builtin_amdgcn_s_barrier();
      __builtin_amdgcn_sched_barrier(0);
      if (t + 1 < nt) stageKV(t + 1, cur ^ 1);

      // QK^T swapped: sacc[ct] = K-tile x Q -> S[kv][q], q = lr lane-local
      f32x4 sacc[4];
#pragma unroll
      for (int ct = 0; ct < 4; ++ct) {
        sacc[ct] = zf;
        const int row = ct * 16 + lr;
#pragma unroll
        for (int kd = 0; kd < 4; ++kd) {
          const short8 kf = *(const short8*)((const char*)Ks + row * 256 +
                                             (((kd * 4 + lh) ^ (row & 7)) * 16));
          sacc[ct] = mfma16(kf, qf[kd], sacc[ct]);
        }
      }

      // softmax: scale, (diag-only) mask, in-lane max + 2 shfl; defer-max skip
      const bool diag = (t == qt);
      float sv[4][4];
      float gmax = -INFINITY;
#pragma unroll
      for (int ct = 0; ct < 4; ++ct) {
#pragma unroll
        for (int r = 0; r < 4; ++r) {
          float s = sacc[ct][r] * scale2;
          if (diag && (kv0 + ct * 16 + 4 * lh + r > qrow)) s = -INFINITY;
          sv[ct][r] = s;
          gmax = fmaxf(gmax, s);
        }
      }
      gmax = fmaxf(gmax, __shfl_xor(gmax, 16, 64));
      gmax = fmaxf(gmax, __shfl_xor(gmax, 32, 64));
      if (!__all(gmax <= Mr + 8.f)) {
        const float mnew = fmaxf(Mr, gmax);
        const float sc = fexp2(Mr - mnew);
        Mr = mnew;
        Lp *= sc;
#pragma unroll
        for (int vt = 0; vt < 8; ++vt) {
#pragma unroll
          for (int r = 0; r < 4; ++r) oacc[vt][r] *= sc;
        }
      }
      unsigned dw[8];
      float ps = 0.f;
#pragma unroll
      for (int ct = 0; ct < 4; ++ct) {
#pragma unroll
        for (int j = 0; j < 2; ++j) {
          const float p0 = fexp2(sv[ct][2 * j] - Mr);
          const float p1 = fexp2(sv[ct][2 * j + 1] - Mr);
          ps += p0 + p1;
          dw[ct * 2 + j] = pk2bf(p0, p1);
        }
      }
      Lp += ps;

      // P roundtrip: 4x b64 write (own slot), 4x b64 read (lh-group gather)
      {
        uint2 t0; t0.x = dw[0]; t0.y = dw[1]; *(uint2*)(myp + 0)  = t0;
        uint2 t1; t1.x = dw[2]; t1.y = dw[3]; *(uint2*)(myp + 8)  = t1;
        uint2 t2; t2.x = dw[4]; t2.y = dw[5]; *(uint2*)(myp + 16) = t2;
        uint2 t3; t3.x = dw[6]; t3.y = dw[7]; *(uint2*)(myp + 24) = t3;
      }
      asm volatile("s_waitcnt lgkmcnt(0)" ::: "memory");
      short8 pf[2];
#pragma unroll
      for (int kb = 0; kb < 2; ++kb) {
        const int ct1 = 2 * kb + (lh >> 1);
        const uint2 a = *(const uint2*)(pw0 + s1 * PSTR + ct1 * 8);
        const uint2 b = *(const uint2*)(pw0 + s2 * PSTR + ct1 * 8);
        uint4 u; u.x = a.x; u.y = a.y; u.z = b.x; u.w = b.y;
        pf[kb] = __builtin_bit_cast(short8, u);
      }
      __builtin_amdgcn_s_setprio(1);
#pragma unroll
      for (int vt = 0; vt < 8; ++vt) {
        const int d = vt * 16 + lr;
#pragma unroll
        for (int kb = 0; kb < 2; ++kb) {
          const short8 vf = *(const short8*)((const char*)Vt + d * 128 +
                                             (((kb * 4 + lh) ^ (lr & 7)) * 16));
          oacc[vt] = mfma16(vf, pf[kb], oacc[vt]);
        }
      }
      __builtin_amdgcn_s_setprio(0);
      cur ^= 1;
    }

    // epilogue: reduce L partials over lh groups, normalize, packed store
    float Ls = Lp;
    Ls += __shfl_xor(Ls, 16, 64);
    Ls += __shfl_xor(Ls, 32, 64);
    const float inv = 1.0f / Ls;
    unsigned short* arow = aout + (size_t)qrow * DMODEL + head * 128;
#pragma unroll
    for (int vt = 0; vt < 8; ++vt) {
      short4v o;
#pragma unroll
      for (int r = 0; r < 4; ++r) o[r] = (short)f2bf(oacc[vt][r] * inv);
      *(short4v*)(arow + vt * 16 + 4 * lh) = o;
    }
    // inter-half barrier: next half's prologue overwrites buffer 0; all
    // waves' reads of this half must be retired (MFMA-consumed) first.
    __builtin_amdgcn_s_barrier();
    __builtin_amdgcn_sched_barrier(0);
  }
}

extern "C" void kernel_launch(void* const* d_in, const int* in_sizes, int n_in,
                              void* d_out, int out_size, void* d_ws, size_t ws_size,
                              hipStream_t stream) {
  (void)in_sizes; (void)n_in; (void)out_size; (void)ws_size;
  const float* x     = (const float*)d_in[0];
  const float* r_cos = (const float*)d_in[1];
  const float* r_sin = (const float*)d_in[2];
  const float* wnorm = (const float*)d_in[3];
  const float* wq    = (const float*)d_in[4];
  const float* wk    = (const float*)d_in[5];
  const float* wv    = (const float*)d_in[6];
  const float* wo    = (const float*)d_in[7];

  // ws layout (bf16 elems): bufA 8.39M | qkvb 10.49M | wT 25.17M | vtg 2.10M = 92.3MB
  unsigned short* bufA = (unsigned short*)d_ws;                  // h, later attn-out
  unsigned short* qkvb = bufA + (size_t)TOK * DMODEL;            // [2048][5120]
  unsigned short* wT   = qkvb + (size_t)TOK * QKV_LD;            // wqkv^T, later wo^T
  unsigned short* vtg  = wT + (size_t)6144 * DMODEL;             // V^T [1024][2048]

  // dynamic-LDS caps (idempotent, host-side; safe under graph capture)
  hipFuncSetAttribute((const void*)k_gemm_big<256, 192, 0>,
                      hipFuncAttributeMaxDynamicSharedMemorySize, 4 * (256 + 192) * 64);
  hipFuncSetAttribute((const void*)k_gemm_big<256, 128, 1>,
                      hipFuncAttributeMaxDynamicSharedMemorySize, 4 * (256 + 128) * 64);
  const int attn_lds = 4 * KVB * 128 * 2 + 256 * PSTR;   // 65536 + 10240 = 75776 B
  hipFuncSetAttribute((const void*)k_attn,
                      hipFuncAttributeMaxDynamicSharedMemorySize, attn_lds);

  k_rmsnorm<<<TOK, 256, 0, stream>>>(x, wnorm, bufA);
  k_wconvert3<<<dim3(64, 64, 3), 256, 0, stream>>>(wq, wk, wv, wT);
  k_gemm_big<256, 192, 0><<<dim3(256), 512, 4 * (256 + 192) * 64, stream>>>(
      bufA, wT, nullptr, qkvb, vtg, r_cos, r_sin, TOK, 6144, DMODEL);
  k_wconvert<<<dim3(64, 64), 256, 0, stream>>>(wo, wT, 4096);   // overlay: wo^T
  k_attn<<<dim3(16, 32), 256, attn_lds, stream>>>(qkvb, vtg, bufA);
  k_gemm_big<256, 128, 1><<<dim3(256), 512, 4 * (256 + 128) * 64, stream>>>(
      bufA, wT, x, d_out, nullptr, nullptr, nullptr, TOK, DMODEL, DMODEL);
}